// Round 7
// baseline (225.851 us; speedup 1.0000x reference)
//
#include <hip/hip_runtime.h>

#define N_NODES 50000
#define N_EDGES 800000
#define NF 128
#define N_GRAPHS 512
#define NSH 8                      // CSR shards (≈ one per XCD)
#define NTOT (NSH * N_NODES)       // 400000 scan elements
#define SCAN_BLOCKS 196            // ceil(400000/2048)

union HU { ushort u; _Float16 h; };
__device__ __forceinline__ float h2f(ushort u) { HU x; x.u = u; return (float)x.h; }
__device__ __forceinline__ ushort f2h(float f) { HU x; x.h = (_Float16)f; return x.u; }

__device__ __forceinline__ void acc8(float* acc, uint4 u) {
  acc[0] += h2f((ushort)(u.x)); acc[1] += h2f((ushort)(u.x >> 16));
  acc[2] += h2f((ushort)(u.y)); acc[3] += h2f((ushort)(u.y >> 16));
  acc[4] += h2f((ushort)(u.z)); acc[5] += h2f((ushort)(u.z >> 16));
  acc[6] += h2f((ushort)(u.w)); acc[7] += h2f((ushort)(u.w >> 16));
}

// ---------------- x (f32) -> xh (fp16) ---------------------------------------
__global__ __launch_bounds__(256) void xcvt(const float* __restrict__ x,
                                            ushort* __restrict__ xh) {
  int i = blockIdx.x * 256 + threadIdx.x;
  float4 v = ((const float4*)x)[i];
  ushort4 o;
  o.x = f2h(v.x); o.y = f2h(v.y); o.z = f2h(v.z); o.w = f2h(v.w);
  ((ushort4*)xh)[i] = o;
}

// ---------------- v[f] = sum_j W2[f][j] * Wfc[j] ------------------------------
__global__ __launch_bounds__(128) void w2wfc(const float* __restrict__ W2,
                                             const float* __restrict__ Wfc,
                                             float* __restrict__ v) {
  int f = threadIdx.x;
  float s = 0.f;
  for (int j = 0; j < 128; j += 4) {
    float4 w = ((const float4*)(W2 + f * 128))[j >> 2];
    float4 c = ((const float4*)Wfc)[j >> 2];
    s += w.x * c.x + w.y * c.y + w.z * c.z + w.w * c.w;
  }
  v[f] = s;
}

// ------------- sharded CSR build: shard s = blocks with blockIdx%8==s --------
__global__ __launch_bounds__(256) void hist_kernel(const int* __restrict__ dst,
                                                   int* __restrict__ deg) {
  unsigned e = blockIdx.x * 256u + threadIdx.x;
  int sh = blockIdx.x & (NSH - 1);
  if (e < N_EDGES) atomicAdd(&deg[sh * N_NODES + dst[e]], 1);
}

__device__ __forceinline__ int block_incl_scan_256(int v, int* warp_sums) {
  const int tid = threadIdx.x;
  const int lane = tid & 63;
  const int w = tid >> 6;
#pragma unroll
  for (int off = 1; off < 64; off <<= 1) {
    int t = __shfl_up(v, off, 64);
    if (lane >= off) v += t;
  }
  if (lane == 63) warp_sums[w] = v;
  __syncthreads();
  int ws = 0;
#pragma unroll
  for (int i = 0; i < 4; ++i) ws += (i < w) ? warp_sums[i] : 0;
  return v + ws;
}

// stage1: 2048 elements per block (8 per thread), per-block inclusive scan
__global__ __launch_bounds__(256) void scan_stage1(const int* __restrict__ deg,
                                                   int* __restrict__ R,
                                                   int* __restrict__ blocksum) {
  __shared__ int warp_sums[4];
  int tid = threadIdx.x;
  int i0 = blockIdx.x * 2048 + tid * 8;
  int v[8];
  int s = 0;
#pragma unroll
  for (int k = 0; k < 8; ++k) {
    int idx = i0 + k;
    v[k] = (idx < NTOT) ? deg[idx] : 0;
    s += v[k];
  }
  int incl = block_incl_scan_256(s, warp_sums);
  int run = incl - s;
#pragma unroll
  for (int k = 0; k < 8; ++k) {
    run += v[k];
    int idx = i0 + k;
    if (idx < NTOT) R[idx + 1] = run;
  }
  if (tid == 255) blocksum[blockIdx.x] = incl;
}

__global__ __launch_bounds__(256) void scan_stage2(int* __restrict__ blocksum) {
  __shared__ int warp_sums[4];
  int tid = threadIdx.x;
  int v = (tid < SCAN_BLOCKS) ? blocksum[tid] : 0;
  int incl = block_incl_scan_256(v, warp_sums);
  if (tid < SCAN_BLOCKS) blocksum[tid] = incl - v;
}

__global__ __launch_bounds__(256) void scan_stage3(int* __restrict__ R,
                                                   const int* __restrict__ blocksum,
                                                   int* __restrict__ cursor) {
  int i = blockIdx.x * 256 + threadIdx.x;
  if (i < NTOT) {
    int r = R[i + 1] + blocksum[i >> 11];
    R[i + 1] = r;
    cursor[i + 1] = r;
  }
  if (i == 0) { R[0] = 0; cursor[0] = 0; }
}

__global__ __launch_bounds__(256) void fill_kernel(const int* __restrict__ src,
                                                   const int* __restrict__ dst,
                                                   int* __restrict__ cursor,
                                                   int* __restrict__ col) {
  unsigned e = blockIdx.x * 256u + threadIdx.x;
  int sh = blockIdx.x & (NSH - 1);
  if (e < N_EDGES) {
    int d = dst[e];
    int pos = atomicAdd(&cursor[sh * N_NODES + d], 1);
    col[pos] = src[e];
  }
}

// ------- gather1: agg_x[n][:] = sum over 8 shard segments of xh[col[j]][:] ---
__global__ __launch_bounds__(256) void gather_x(const ushort* __restrict__ xh,
                                                const int* __restrict__ R,
                                                const int* __restrict__ col,
                                                float* __restrict__ outf) {
  unsigned gid = blockIdx.x * 256u + threadIdx.x;
  unsigned n = gid >> 5;
  unsigned q = gid & 31u;
  if (n >= N_NODES) return;
  float4 acc = float4{0.f, 0.f, 0.f, 0.f};
#pragma unroll
  for (int s = 0; s < NSH; ++s) {
    int base = s * N_NODES + n;
    int j0 = R[base], j1 = R[base + 1];
    int j = j0;
    for (; j + 2 <= j1; j += 2) {
      int s0 = col[j], s1 = col[j + 1];
      ushort4 a = ((const ushort4*)xh)[(size_t)s0 * 32 + q];
      ushort4 b = ((const ushort4*)xh)[(size_t)s1 * 32 + q];
      acc.x += h2f(a.x) + h2f(b.x);
      acc.y += h2f(a.y) + h2f(b.y);
      acc.z += h2f(a.z) + h2f(b.z);
      acc.w += h2f(a.w) + h2f(b.w);
    }
    if (j < j1) {
      ushort4 a = ((const ushort4*)xh)[(size_t)col[j] * 32 + q];
      acc.x += h2f(a.x); acc.y += h2f(a.y); acc.z += h2f(a.z); acc.w += h2f(a.w);
    }
  }
  ((float4*)outf)[(size_t)n * 32 + q] = acc;
}

// -------- GEMM: hA(fp16) = relu(A[M,128] @ W[128,128]) -----------------------
__global__ __launch_bounds__(256) void gemm_relu_h(const float* __restrict__ A,
                                                   const float* __restrict__ W,
                                                   ushort* __restrict__ hA, int M) {
  __shared__ float sW[32][128];
  __shared__ float sA[64][36];
  const int tid = threadIdx.x;
  const int row0 = blockIdx.x * 64;
  const int rg = tid >> 4;
  const int cg = tid & 15;

  float4 acc[4][2];
#pragma unroll
  for (int i = 0; i < 4; ++i) {
    acc[i][0] = float4{0.f, 0.f, 0.f, 0.f};
    acc[i][1] = float4{0.f, 0.f, 0.f, 0.f};
  }

  for (int kt = 0; kt < 128; kt += 32) {
#pragma unroll
    for (int i = 0; i < 4; ++i) {
      int idx = i * 256 + tid;
      int r = idx >> 5, c4 = idx & 31;
      ((float4*)&sW[r][0])[c4] = ((const float4*)W)[(kt + r) * 32 + c4];
    }
#pragma unroll
    for (int i = 0; i < 2; ++i) {
      int idx = i * 256 + tid;
      int r = idx >> 3, c4 = idx & 7;
      int gr = row0 + r;
      float4 v = float4{0.f, 0.f, 0.f, 0.f};
      if (gr < M) v = ((const float4*)A)[gr * 32 + (kt >> 2) + c4];
      *(float4*)&sA[r][c4 * 4] = v;
    }
    __syncthreads();

#pragma unroll
    for (int k = 0; k < 32; k += 4) {
      float4 a0 = *(const float4*)&sA[rg * 4 + 0][k];
      float4 a1 = *(const float4*)&sA[rg * 4 + 1][k];
      float4 a2 = *(const float4*)&sA[rg * 4 + 2][k];
      float4 a3 = *(const float4*)&sA[rg * 4 + 3][k];
      const float* ap0 = (const float*)&a0;
      const float* ap1 = (const float*)&a1;
      const float* ap2 = (const float*)&a2;
      const float* ap3 = (const float*)&a3;
#pragma unroll
      for (int kk = 0; kk < 4; ++kk) {
        float4 w0 = *(const float4*)&sW[k + kk][cg * 8];
        float4 w1 = *(const float4*)&sW[k + kk][cg * 8 + 4];
        float a0k = ap0[kk], a1k = ap1[kk], a2k = ap2[kk], a3k = ap3[kk];
#define FMA_ROW(I, AK)                                                         \
        acc[I][0].x += AK * w0.x; acc[I][0].y += AK * w0.y;                    \
        acc[I][0].z += AK * w0.z; acc[I][0].w += AK * w0.w;                    \
        acc[I][1].x += AK * w1.x; acc[I][1].y += AK * w1.y;                    \
        acc[I][1].z += AK * w1.z; acc[I][1].w += AK * w1.w;
        FMA_ROW(0, a0k)
        FMA_ROW(1, a1k)
        FMA_ROW(2, a2k)
        FMA_ROW(3, a3k)
#undef FMA_ROW
      }
    }
    __syncthreads();
  }

#pragma unroll
  for (int i = 0; i < 4; ++i) {
    int gr = row0 + rg * 4 + i;
    if (gr < M) {
      float4 a0 = acc[i][0], a1 = acc[i][1];
      a0.x = fmaxf(a0.x, 0.f); a0.y = fmaxf(a0.y, 0.f);
      a0.z = fmaxf(a0.z, 0.f); a0.w = fmaxf(a0.w, 0.f);
      a1.x = fmaxf(a1.x, 0.f); a1.y = fmaxf(a1.y, 0.f);
      a1.z = fmaxf(a1.z, 0.f); a1.w = fmaxf(a1.w, 0.f);
      uint4 o;
      o.x = (uint)f2h(a0.x) | ((uint)f2h(a0.y) << 16);
      o.y = (uint)f2h(a0.z) | ((uint)f2h(a0.w) << 16);
      o.z = (uint)f2h(a1.x) | ((uint)f2h(a1.y) << 16);
      o.w = (uint)f2h(a1.z) | ((uint)f2h(a1.w) << 16);
      ((uint4*)hA)[gr * 16 + cg] = o;
    }
  }
}

// ------- pool: poolpart[sh][g][:] = sum of hA[col[j]] over shard sh's edges
// of graph g (contiguous range; batch sorted, shard node-major). No atomics.
__global__ __launch_bounds__(256) void pool_split(const ushort* __restrict__ hA,
                                                  const int* __restrict__ R,
                                                  const int* __restrict__ col,
                                                  const int* __restrict__ batch,
                                                  float* __restrict__ poolpart) {
  __shared__ float part[16][132];
  const int g = blockIdx.x;
  const int sh = blockIdx.y;
  const int q = threadIdx.x & 15;
  const int eo = threadIdx.x >> 4;

  int lo = 0, hi = N_NODES;
  while (lo < hi) { int m = (lo + hi) >> 1; if (batch[m] < g) lo = m + 1; else hi = m; }
  int s0 = lo;
  lo = 0; hi = N_NODES;
  while (lo < hi) { int m = (lo + hi) >> 1; if (batch[m] <= g) lo = m + 1; else hi = m; }
  int s1 = lo;

  int j0 = R[sh * N_NODES + s0];
  int j1 = R[sh * N_NODES + s1];

  float acc[8] = {0.f, 0.f, 0.f, 0.f, 0.f, 0.f, 0.f, 0.f};
  for (int j = j0 + eo; j < j1; j += 16) {
    uint4 u = ((const uint4*)hA)[(size_t)col[j] * 16 + q];
    acc8(acc, u);
  }
#pragma unroll
  for (int k = 0; k < 8; ++k) part[eo][q * 8 + k] = acc[k];
  __syncthreads();

  if (threadIdx.x < 128) {
    int f = threadIdx.x;
    float ss = 0.f;
#pragma unroll
    for (int i = 0; i < 16; ++i) ss += part[i][f];
    poolpart[((size_t)sh * N_GRAPHS + g) * NF + f] = ss;
  }
}

// ------- finish: z[g] = (sum_sh poolpart[sh][g] / cnt) . v ; sigmoid ---------
__global__ __launch_bounds__(128) void pool_finish(const float* __restrict__ poolpart,
                                                   const int* __restrict__ batch,
                                                   const float* __restrict__ v,
                                                   float* __restrict__ out) {
  __shared__ float reds[2];
  int g = blockIdx.x, f = threadIdx.x;

  int lo = 0, hi = N_NODES;
  while (lo < hi) { int m = (lo + hi) >> 1; if (batch[m] < g) lo = m + 1; else hi = m; }
  int s0 = lo;
  lo = 0; hi = N_NODES;
  while (lo < hi) { int m = (lo + hi) >> 1; if (batch[m] <= g) lo = m + 1; else hi = m; }
  int s1 = lo;

  float ss = 0.f;
#pragma unroll
  for (int i = 0; i < NSH; ++i)
    ss += poolpart[((size_t)i * N_GRAPHS + g) * NF + f];

  float cnt = fmaxf((float)(s1 - s0), 1.0f);
  float z = (ss / cnt) * v[f];
#pragma unroll
  for (int off = 32; off > 0; off >>= 1) z += __shfl_down(z, off, 64);
  if (f == 0) reds[0] = z;
  if (f == 64) reds[1] = z;
  __syncthreads();
  if (f == 0) {
    float zz = reds[0] + reds[1];
    out[g] = 1.0f / (1.0f + expf(-zz));
  }
}

extern "C" void kernel_launch(void* const* d_in, const int* in_sizes, int n_in,
                              void* d_out, int out_size, void* d_ws, size_t ws_size,
                              hipStream_t stream) {
  const float* x   = (const float*)d_in[0];
  const int*   ei  = (const int*)d_in[1];
  const int*   src = ei;               // edge_index[0]
  const int*   dst = ei + N_EDGES;     // edge_index[1]
  const int* batch = (const int*)d_in[2];
  const float* W1  = (const float*)d_in[3];
  const float* W2  = (const float*)d_in[4];
  const float* Wfc = (const float*)d_in[5];
  float* out = (float*)d_out;

  float*  bufA = (float*)d_ws;                           // 6.4M f32 (agg_x)
  ushort* xh   = (ushort*)(bufA + (size_t)N_NODES * NF); // 6.4M fp16
  ushort* hA   = xh + (size_t)N_NODES * NF;              // 6.4M fp16
  float* poolpart = (float*)(hA + (size_t)N_NODES * NF); // NSH*512*128 f32
  int* deg     = (int*)poolpart;         // alias: deg dead before poolpart live
  int* R       = (int*)(poolpart + (size_t)NSH * N_GRAPHS * NF); // NTOT+1
  int* cursor  = R + NTOT + 1;           // NTOT+1
  int* col     = cursor + NTOT + 1;      // N_EDGES
  int* blocksum = col + N_EDGES;         // SCAN_BLOCKS
  float* v     = (float*)(blocksum + SCAN_BLOCKS + 4);   // 128

  const int gemm_grid = (N_NODES + 63) / 64;            // 782
  const int edge_grid = (N_EDGES + 255) / 256;          // 3125
  const int agg_grid  = (N_NODES * 32 + 255) / 256;     // 6250
  const int cvt_grid  = (N_NODES * NF / 4) / 256;       // 6250 exact
  const int st3_grid  = (NTOT + 255) / 256;             // 1563

  // --- build sharded CSR (dst -> srcs), shard = blockIdx%8 ≈ XCD ---
  hipMemsetAsync(deg, 0, NTOT * sizeof(int), stream);
  hist_kernel<<<edge_grid, 256, 0, stream>>>(dst, deg);
  scan_stage1<<<SCAN_BLOCKS, 256, 0, stream>>>(deg, R, blocksum);
  scan_stage2<<<1, 256, 0, stream>>>(blocksum);
  scan_stage3<<<st3_grid, 256, 0, stream>>>(R, blocksum, cursor);
  fill_kernel<<<edge_grid, 256, 0, stream>>>(src, dst, cursor, col);

  // --- precompute fp16 x and v = W2@Wfc ---
  xcvt<<<cvt_grid, 256, 0, stream>>>(x, xh);
  w2wfc<<<1, 128, 0, stream>>>(W2, Wfc, v);

  // --- conv1: agg_x = gather(xh); hA = relu(agg_x @ W1) (fp16) ---
  gather_x<<<agg_grid, 256, 0, stream>>>(xh, R, col, bufA);
  gemm_relu_h<<<gemm_grid, 256, 0, stream>>>(bufA, W1, hA, N_NODES);

  // --- conv2-agg + pool: per-(graph,shard) private partial sums, no atomics --
  pool_split<<<dim3(N_GRAPHS, NSH), 256, 0, stream>>>(hA, R, col, batch, poolpart);
  pool_finish<<<N_GRAPHS, 128, 0, stream>>>(poolpart, batch, v, out);
}

// Round 8
// 187.063 us; speedup vs baseline: 1.2074x; 1.2074x over previous
//
#include <hip/hip_runtime.h>

#define N_NODES 50000
#define N_EDGES 800000
#define NF 128
#define N_GRAPHS 512
#define STRIDE 64       // fixed CSR slots/node; P(deg>64) ~ 1e-13 for Poisson(16)
#define NS 2            // pool slices per graph

union HU { ushort u; _Float16 h; };
__device__ __forceinline__ float h2f(ushort u) { HU x; x.u = u; return (float)x.h; }
__device__ __forceinline__ ushort f2h(float f) { HU x; x.h = (_Float16)f; return x.u; }

__device__ __forceinline__ void acc8(float* acc, uint4 u) {
  acc[0] += h2f((ushort)(u.x)); acc[1] += h2f((ushort)(u.x >> 16));
  acc[2] += h2f((ushort)(u.y)); acc[3] += h2f((ushort)(u.y >> 16));
  acc[4] += h2f((ushort)(u.z)); acc[5] += h2f((ushort)(u.z >> 16));
  acc[6] += h2f((ushort)(u.w)); acc[7] += h2f((ushort)(u.w >> 16));
}

// ---------------- x (f32) -> xh (fp16) ---------------------------------------
__global__ __launch_bounds__(256) void xcvt(const float* __restrict__ x,
                                            ushort* __restrict__ xh) {
  int i = blockIdx.x * 256 + threadIdx.x;
  float4 v = ((const float4*)x)[i];
  ushort4 o;
  o.x = f2h(v.x); o.y = f2h(v.y); o.z = f2h(v.z); o.w = f2h(v.w);
  ((ushort4*)xh)[i] = o;
}

// ---------------- v[f] = sum_j W2[f][j] * Wfc[j] ------------------------------
__global__ __launch_bounds__(128) void w2wfc(const float* __restrict__ W2,
                                             const float* __restrict__ Wfc,
                                             float* __restrict__ v) {
  int f = threadIdx.x;
  float s = 0.f;
  for (int j = 0; j < 128; j += 4) {
    float4 w = ((const float4*)(W2 + f * 128))[j >> 2];
    float4 c = ((const float4*)Wfc)[j >> 2];
    s += w.x * c.x + w.y * c.y + w.z * c.z + w.w * c.w;
  }
  v[f] = s;
}

// ------------- fixed-stride CSR build: one kernel, no scan -------------------
__global__ __launch_bounds__(256) void build_csr(const int* __restrict__ src,
                                                 const int* __restrict__ dst,
                                                 int* __restrict__ deg,
                                                 ushort* __restrict__ col16) {
  unsigned e = blockIdx.x * 256u + threadIdx.x;
  if (e < N_EDGES) {
    int d = dst[e];
    int slot = atomicAdd(&deg[d], 1);
    col16[d * STRIDE + slot] = (ushort)src[e];
  }
}

// ------- gather1: agg_x[n][:] = sum_{slots} xh[col16[n][s]][:]  (f32 out) ----
// One node per wave64: 4 edge-groups x 16 feat-lanes (uint4 = 8 fp16).
// Unroll 2 -> 8 edge-row requests in flight per wave.
__global__ __launch_bounds__(256) void gather_x(const ushort* __restrict__ xh,
                                                const int* __restrict__ deg,
                                                const ushort* __restrict__ col16,
                                                float* __restrict__ outf) {
  int n = (blockIdx.x * 256 + threadIdx.x) >> 6;
  if (n >= N_NODES) return;
  const int lane = threadIdx.x & 63;
  const int eg = lane >> 4;    // 0..3 edge group
  const int fl = lane & 15;    // feat lane: 8 fp16 = 16B

  int dg = deg[n];
  const ushort* cp = col16 + (size_t)n * STRIDE;
  float acc[8] = {0.f, 0.f, 0.f, 0.f, 0.f, 0.f, 0.f, 0.f};

  int j = eg;
  for (; j + 4 < dg; j += 8) {
    int s0 = cp[j], s1 = cp[j + 4];
    uint4 a = ((const uint4*)xh)[(size_t)s0 * 16 + fl];
    uint4 b = ((const uint4*)xh)[(size_t)s1 * 16 + fl];
    acc8(acc, a);
    acc8(acc, b);
  }
  if (j < dg) {
    uint4 a = ((const uint4*)xh)[(size_t)cp[j] * 16 + fl];
    acc8(acc, a);
  }

#pragma unroll
  for (int k = 0; k < 8; ++k) {
    acc[k] += __shfl_xor(acc[k], 16, 64);
    acc[k] += __shfl_xor(acc[k], 32, 64);
  }
  if (eg == 0) {
    float4 o0 = {acc[0], acc[1], acc[2], acc[3]};
    float4 o1 = {acc[4], acc[5], acc[6], acc[7]};
    ((float4*)outf)[(size_t)n * 32 + fl * 2 + 0] = o0;
    ((float4*)outf)[(size_t)n * 32 + fl * 2 + 1] = o1;
  }
}

// -------- GEMM: hA(fp16) = relu(A[M,128] @ W[128,128]) -----------------------
__global__ __launch_bounds__(256) void gemm_relu_h(const float* __restrict__ A,
                                                   const float* __restrict__ W,
                                                   ushort* __restrict__ hA, int M) {
  __shared__ float sW[32][128];
  __shared__ float sA[64][36];
  const int tid = threadIdx.x;
  const int row0 = blockIdx.x * 64;
  const int rg = tid >> 4;
  const int cg = tid & 15;

  float4 acc[4][2];
#pragma unroll
  for (int i = 0; i < 4; ++i) {
    acc[i][0] = float4{0.f, 0.f, 0.f, 0.f};
    acc[i][1] = float4{0.f, 0.f, 0.f, 0.f};
  }

  for (int kt = 0; kt < 128; kt += 32) {
#pragma unroll
    for (int i = 0; i < 4; ++i) {
      int idx = i * 256 + tid;
      int r = idx >> 5, c4 = idx & 31;
      ((float4*)&sW[r][0])[c4] = ((const float4*)W)[(kt + r) * 32 + c4];
    }
#pragma unroll
    for (int i = 0; i < 2; ++i) {
      int idx = i * 256 + tid;
      int r = idx >> 3, c4 = idx & 7;
      int gr = row0 + r;
      float4 v = float4{0.f, 0.f, 0.f, 0.f};
      if (gr < M) v = ((const float4*)A)[gr * 32 + (kt >> 2) + c4];
      *(float4*)&sA[r][c4 * 4] = v;
    }
    __syncthreads();

#pragma unroll
    for (int k = 0; k < 32; k += 4) {
      float4 a0 = *(const float4*)&sA[rg * 4 + 0][k];
      float4 a1 = *(const float4*)&sA[rg * 4 + 1][k];
      float4 a2 = *(const float4*)&sA[rg * 4 + 2][k];
      float4 a3 = *(const float4*)&sA[rg * 4 + 3][k];
      const float* ap0 = (const float*)&a0;
      const float* ap1 = (const float*)&a1;
      const float* ap2 = (const float*)&a2;
      const float* ap3 = (const float*)&a3;
#pragma unroll
      for (int kk = 0; kk < 4; ++kk) {
        float4 w0 = *(const float4*)&sW[k + kk][cg * 8];
        float4 w1 = *(const float4*)&sW[k + kk][cg * 8 + 4];
        float a0k = ap0[kk], a1k = ap1[kk], a2k = ap2[kk], a3k = ap3[kk];
#define FMA_ROW(I, AK)                                                         \
        acc[I][0].x += AK * w0.x; acc[I][0].y += AK * w0.y;                    \
        acc[I][0].z += AK * w0.z; acc[I][0].w += AK * w0.w;                    \
        acc[I][1].x += AK * w1.x; acc[I][1].y += AK * w1.y;                    \
        acc[I][1].z += AK * w1.z; acc[I][1].w += AK * w1.w;
        FMA_ROW(0, a0k)
        FMA_ROW(1, a1k)
        FMA_ROW(2, a2k)
        FMA_ROW(3, a3k)
#undef FMA_ROW
      }
    }
    __syncthreads();
  }

#pragma unroll
  for (int i = 0; i < 4; ++i) {
    int gr = row0 + rg * 4 + i;
    if (gr < M) {
      float4 a0 = acc[i][0], a1 = acc[i][1];
      a0.x = fmaxf(a0.x, 0.f); a0.y = fmaxf(a0.y, 0.f);
      a0.z = fmaxf(a0.z, 0.f); a0.w = fmaxf(a0.w, 0.f);
      a1.x = fmaxf(a1.x, 0.f); a1.y = fmaxf(a1.y, 0.f);
      a1.z = fmaxf(a1.z, 0.f); a1.w = fmaxf(a1.w, 0.f);
      uint4 o;
      o.x = (uint)f2h(a0.x) | ((uint)f2h(a0.y) << 16);
      o.y = (uint)f2h(a0.z) | ((uint)f2h(a0.w) << 16);
      o.z = (uint)f2h(a1.x) | ((uint)f2h(a1.y) << 16);
      o.w = (uint)f2h(a1.z) | ((uint)f2h(a1.w) << 16);
      ((uint4*)hA)[gr * 16 + cg] = o;
    }
  }
}

// ------- pool: poolpart[s][g][:] = sum over nodes n of graph g (slice s) of
// sum_{slots} hA[col16[n][j]][:].  Register accumulation, no atomics.
__global__ __launch_bounds__(256) void pool_split(const ushort* __restrict__ hA,
                                                  const int* __restrict__ deg,
                                                  const ushort* __restrict__ col16,
                                                  const int* __restrict__ batch,
                                                  float* __restrict__ poolpart) {
  __shared__ float part[4][128];
  const int g = blockIdx.x;
  const int s = blockIdx.y;
  const int tid = threadIdx.x;
  const int wv = tid >> 6;
  const int lane = tid & 63;
  const int eg = lane >> 4;
  const int fl = lane & 15;

  int lo = 0, hi = N_NODES;
  while (lo < hi) { int m = (lo + hi) >> 1; if (batch[m] < g) lo = m + 1; else hi = m; }
  int s0 = lo;
  lo = 0; hi = N_NODES;
  while (lo < hi) { int m = (lo + hi) >> 1; if (batch[m] <= g) lo = m + 1; else hi = m; }
  int s1 = lo;

  float acc[8] = {0.f, 0.f, 0.f, 0.f, 0.f, 0.f, 0.f, 0.f};
  for (int n = s0 + s * 4 + wv; n < s1; n += NS * 4) {
    int dg = deg[n];
    const ushort* cp = col16 + (size_t)n * STRIDE;
    int j = eg;
    for (; j + 4 < dg; j += 8) {
      int a0 = cp[j], a1 = cp[j + 4];
      uint4 u0 = ((const uint4*)hA)[(size_t)a0 * 16 + fl];
      uint4 u1 = ((const uint4*)hA)[(size_t)a1 * 16 + fl];
      acc8(acc, u0);
      acc8(acc, u1);
    }
    if (j < dg) {
      uint4 u0 = ((const uint4*)hA)[(size_t)cp[j] * 16 + fl];
      acc8(acc, u0);
    }
  }

#pragma unroll
  for (int k = 0; k < 8; ++k) {
    acc[k] += __shfl_xor(acc[k], 16, 64);
    acc[k] += __shfl_xor(acc[k], 32, 64);
  }
  if (eg == 0) {
#pragma unroll
    for (int k = 0; k < 8; ++k) part[wv][fl * 8 + k] = acc[k];
  }
  __syncthreads();

  if (tid < 128) {
    float ss = part[0][tid] + part[1][tid] + part[2][tid] + part[3][tid];
    poolpart[((size_t)s * N_GRAPHS + g) * NF + tid] = ss;
  }
}

// ------- finish: z[g] = (sum_s poolpart[s][g] / cnt) . v ; sigmoid -----------
__global__ __launch_bounds__(128) void pool_finish(const float* __restrict__ poolpart,
                                                   const int* __restrict__ batch,
                                                   const float* __restrict__ v,
                                                   float* __restrict__ out) {
  __shared__ float reds[2];
  int g = blockIdx.x, f = threadIdx.x;

  int lo = 0, hi = N_NODES;
  while (lo < hi) { int m = (lo + hi) >> 1; if (batch[m] < g) lo = m + 1; else hi = m; }
  int s0 = lo;
  lo = 0; hi = N_NODES;
  while (lo < hi) { int m = (lo + hi) >> 1; if (batch[m] <= g) lo = m + 1; else hi = m; }
  int s1 = lo;

  float ss = 0.f;
#pragma unroll
  for (int i = 0; i < NS; ++i)
    ss += poolpart[((size_t)i * N_GRAPHS + g) * NF + f];

  float cnt = fmaxf((float)(s1 - s0), 1.0f);
  float z = (ss / cnt) * v[f];
#pragma unroll
  for (int off = 32; off > 0; off >>= 1) z += __shfl_down(z, off, 64);
  if (f == 0) reds[0] = z;
  if (f == 64) reds[1] = z;
  __syncthreads();
  if (f == 0) {
    float zz = reds[0] + reds[1];
    out[g] = 1.0f / (1.0f + expf(-zz));
  }
}

extern "C" void kernel_launch(void* const* d_in, const int* in_sizes, int n_in,
                              void* d_out, int out_size, void* d_ws, size_t ws_size,
                              hipStream_t stream) {
  const float* x   = (const float*)d_in[0];
  const int*   ei  = (const int*)d_in[1];
  const int*   src = ei;               // edge_index[0]
  const int*   dst = ei + N_EDGES;     // edge_index[1]
  const int* batch = (const int*)d_in[2];
  const float* W1  = (const float*)d_in[3];
  const float* W2  = (const float*)d_in[4];
  const float* Wfc = (const float*)d_in[5];
  float* out = (float*)d_out;

  float*  bufA = (float*)d_ws;                           // 6.4M f32 (agg_x)
  ushort* xh   = (ushort*)(bufA + (size_t)N_NODES * NF); // 6.4M fp16
  ushort* hA   = xh + (size_t)N_NODES * NF;              // 6.4M fp16
  ushort* col16 = hA + (size_t)N_NODES * NF;             // 50000*64 ushort
  float* poolpart = (float*)(col16 + (size_t)N_NODES * STRIDE); // NS*512*128
  int* deg     = (int*)(poolpart + (size_t)NS * N_GRAPHS * NF); // 50000
  float* v     = (float*)(deg + N_NODES);                // 128

  const int gemm_grid = (N_NODES + 63) / 64;            // 782
  const int edge_grid = (N_EDGES + 255) / 256;          // 3125
  const int cvt_grid  = (N_NODES * NF / 4) / 256;       // 6250 exact
  const int gath_grid = (N_NODES * 64 + 255) / 256;     // 12500

  // --- build fixed-stride CSR (dst -> srcs) in one pass ---
  hipMemsetAsync(deg, 0, N_NODES * sizeof(int), stream);
  build_csr<<<edge_grid, 256, 0, stream>>>(src, dst, deg, col16);

  // --- precompute fp16 x and v = W2@Wfc ---
  xcvt<<<cvt_grid, 256, 0, stream>>>(x, xh);
  w2wfc<<<1, 128, 0, stream>>>(W2, Wfc, v);

  // --- conv1: agg_x = gather(xh); hA = relu(agg_x @ W1) (fp16) ---
  gather_x<<<gath_grid, 256, 0, stream>>>(xh, deg, col16, bufA);
  gemm_relu_h<<<gemm_grid, 256, 0, stream>>>(bufA, W1, hA, N_NODES);

  // --- conv2-agg + pool: per-(graph,slice) register accumulation ---
  pool_split<<<dim3(N_GRAPHS, NS), 256, 0, stream>>>(hA, deg, col16, batch,
                                                     poolpart);
  pool_finish<<<N_GRAPHS, 128, 0, stream>>>(poolpart, batch, v, out);
}

// Round 9
// 157.754 us; speedup vs baseline: 1.4317x; 1.1858x over previous
//
#include <hip/hip_runtime.h>

#define N_NODES 50000
#define N_EDGES 800000
#define NF 128
#define N_GRAPHS 512
#define STRIDE 64        // fixed CSR slots/node; P(deg>64) ~ 1e-13 for Poisson(16)
#define NS 2             // pool slices per graph

#define NBINS 391        // ceil(50000/128) bins of 128 nodes (dst>>7)
#define NBLK 196         // edge blocks: ceil(800000/4096)
#define EPB 4096         // edges per block in binning passes
#define SC_N (NBINS * NBLK)   // 76636 scan elements
#define SC_BLOCKS 38     // ceil(SC_N/2048)

union HU { ushort u; _Float16 h; };
__device__ __forceinline__ float h2f(ushort u) { HU x; x.u = u; return (float)x.h; }
__device__ __forceinline__ ushort f2h(float f) { HU x; x.h = (_Float16)f; return x.u; }

__device__ __forceinline__ void acc8(float* acc, uint4 u) {
  acc[0] += h2f((ushort)(u.x)); acc[1] += h2f((ushort)(u.x >> 16));
  acc[2] += h2f((ushort)(u.y)); acc[3] += h2f((ushort)(u.y >> 16));
  acc[4] += h2f((ushort)(u.z)); acc[5] += h2f((ushort)(u.z >> 16));
  acc[6] += h2f((ushort)(u.w)); acc[7] += h2f((ushort)(u.w >> 16));
}

// ---------------- x (f32) -> xh (fp16) ---------------------------------------
__global__ __launch_bounds__(256) void xcvt(const float* __restrict__ x,
                                            ushort* __restrict__ xh) {
  int i = blockIdx.x * 256 + threadIdx.x;
  float4 v = ((const float4*)x)[i];
  ushort4 o;
  o.x = f2h(v.x); o.y = f2h(v.y); o.z = f2h(v.z); o.w = f2h(v.w);
  ((ushort4*)xh)[i] = o;
}

// ---------------- v[f] = sum_j W2[f][j] * Wfc[j] ------------------------------
__global__ __launch_bounds__(128) void w2wfc(const float* __restrict__ W2,
                                             const float* __restrict__ Wfc,
                                             float* __restrict__ v) {
  int f = threadIdx.x;
  float s = 0.f;
  for (int j = 0; j < 128; j += 4) {
    float4 w = ((const float4*)(W2 + f * 128))[j >> 2];
    float4 c = ((const float4*)Wfc)[j >> 2];
    s += w.x * c.x + w.y * c.y + w.z * c.z + w.w * c.w;
  }
  v[f] = s;
}

// ======== CSR build, phase A: bin edges by dst>>7 (128-node bins) ============
// A1: per-block LDS histogram -> bhist[bin*NBLK + block]
__global__ __launch_bounds__(256) void bin_count(const int* __restrict__ dst,
                                                 int* __restrict__ bhist) {
  __shared__ int hist[NBINS];
  for (int i = threadIdx.x; i < NBINS; i += 256) hist[i] = 0;
  __syncthreads();
  int e0 = blockIdx.x * EPB;
  int e1 = e0 + EPB; if (e1 > N_EDGES) e1 = N_EDGES;
  for (int e = e0 + threadIdx.x; e < e1; e += 256)
    atomicAdd(&hist[dst[e] >> 7], 1);
  __syncthreads();
  for (int i = threadIdx.x; i < NBINS; i += 256)
    bhist[i * NBLK + blockIdx.x] = hist[i];
}

__device__ __forceinline__ int block_incl_scan_256(int v, int* warp_sums) {
  const int tid = threadIdx.x;
  const int lane = tid & 63;
  const int w = tid >> 6;
#pragma unroll
  for (int off = 1; off < 64; off <<= 1) {
    int t = __shfl_up(v, off, 64);
    if (lane >= off) v += t;
  }
  if (lane == 63) warp_sums[w] = v;
  __syncthreads();
  int ws = 0;
#pragma unroll
  for (int i = 0; i < 4; ++i) ws += (i < w) ? warp_sums[i] : 0;
  return v + ws;
}

// scan stage1: 2048 elements/block (8/thread) of bhist -> R[i+1] (block-local)
__global__ __launch_bounds__(256) void scan_stage1(const int* __restrict__ in,
                                                   int* __restrict__ R,
                                                   int* __restrict__ blocksum) {
  __shared__ int warp_sums[4];
  int tid = threadIdx.x;
  int i0 = blockIdx.x * 2048 + tid * 8;
  int v[8];
  int s = 0;
#pragma unroll
  for (int k = 0; k < 8; ++k) {
    int idx = i0 + k;
    v[k] = (idx < SC_N) ? in[idx] : 0;
    s += v[k];
  }
  int incl = block_incl_scan_256(s, warp_sums);
  int run = incl - s;
#pragma unroll
  for (int k = 0; k < 8; ++k) {
    run += v[k];
    int idx = i0 + k;
    if (idx < SC_N) R[idx + 1] = run;
  }
  if (tid == 255) blocksum[blockIdx.x] = incl;
}

__global__ __launch_bounds__(256) void scan_stage2(int* __restrict__ blocksum) {
  __shared__ int warp_sums[4];
  int tid = threadIdx.x;
  int v = (tid < SC_BLOCKS) ? blocksum[tid] : 0;
  int incl = block_incl_scan_256(v, warp_sums);
  if (tid < SC_BLOCKS) blocksum[tid] = incl - v;
}

__global__ __launch_bounds__(256) void scan_stage3(int* __restrict__ R,
                                                   const int* __restrict__ blocksum) {
  int i = blockIdx.x * 256 + threadIdx.x;
  if (i < SC_N) R[i + 1] += blocksum[i >> 11];
  if (i == 0) R[0] = 0;
}

// A2: scatter packed edges (dst<<16 | src) into bin-grouped ebuf
__global__ __launch_bounds__(256) void bin_scatter(const int* __restrict__ src,
                                                   const int* __restrict__ dst,
                                                   const int* __restrict__ R,
                                                   uint* __restrict__ ebuf) {
  __shared__ int cur[NBINS];
  for (int i = threadIdx.x; i < NBINS; i += 256) cur[i] = 0;
  __syncthreads();
  int e0 = blockIdx.x * EPB;
  int e1 = e0 + EPB; if (e1 > N_EDGES) e1 = N_EDGES;
  for (int e = e0 + threadIdx.x; e < e1; e += 256) {
    int d = dst[e];
    int b = d >> 7;
    int loc = atomicAdd(&cur[b], 1);
    ebuf[R[b * NBLK + blockIdx.x] + loc] = ((uint)d << 16) | (uint)src[e];
  }
}

// ======== CSR build, phase B: one block per bin -> col16 window + deg ========
__global__ __launch_bounds__(256) void csr_from_bins(const uint* __restrict__ ebuf,
                                                     const int* __restrict__ R,
                                                     int* __restrict__ deg,
                                                     ushort* __restrict__ col16) {
  __shared__ int dl[128];
  const int bin = blockIdx.x;
  const int n0 = bin << 7;
  if (threadIdx.x < 128) dl[threadIdx.x] = 0;
  __syncthreads();
  int j0 = R[bin * NBLK];
  int j1 = R[(bin + 1) * NBLK];
  for (int j = j0 + threadIdx.x; j < j1; j += 256) {
    uint e = ebuf[j];
    int d = (int)(e >> 16);
    int slot = atomicAdd(&dl[d - n0], 1);
    col16[(size_t)d * STRIDE + slot] = (ushort)(e & 0xFFFFu);
  }
  __syncthreads();
  int cnt = N_NODES - n0; if (cnt > 128) cnt = 128;
  if (threadIdx.x < cnt) deg[n0 + threadIdx.x] = dl[threadIdx.x];
}

// ------- gather1: agg_x[n][:] = sum_{slots} xh[col16[n][s]][:]  (f32 out) ----
// One node per wave64: 4 edge-groups x 16 feat-lanes (uint4 = 8 fp16).
__global__ __launch_bounds__(256) void gather_x(const ushort* __restrict__ xh,
                                                const int* __restrict__ deg,
                                                const ushort* __restrict__ col16,
                                                float* __restrict__ outf) {
  int n = (blockIdx.x * 256 + threadIdx.x) >> 6;
  if (n >= N_NODES) return;
  const int lane = threadIdx.x & 63;
  const int eg = lane >> 4;    // 0..3 edge group
  const int fl = lane & 15;    // feat lane: 8 fp16 = 16B

  int dg = deg[n];
  const ushort* cp = col16 + (size_t)n * STRIDE;
  float acc[8] = {0.f, 0.f, 0.f, 0.f, 0.f, 0.f, 0.f, 0.f};

  int j = eg;
  for (; j + 4 < dg; j += 8) {
    int s0 = cp[j], s1 = cp[j + 4];
    uint4 a = ((const uint4*)xh)[(size_t)s0 * 16 + fl];
    uint4 b = ((const uint4*)xh)[(size_t)s1 * 16 + fl];
    acc8(acc, a);
    acc8(acc, b);
  }
  if (j < dg) {
    uint4 a = ((const uint4*)xh)[(size_t)cp[j] * 16 + fl];
    acc8(acc, a);
  }

#pragma unroll
  for (int k = 0; k < 8; ++k) {
    acc[k] += __shfl_xor(acc[k], 16, 64);
    acc[k] += __shfl_xor(acc[k], 32, 64);
  }
  if (eg == 0) {
    float4 o0 = {acc[0], acc[1], acc[2], acc[3]};
    float4 o1 = {acc[4], acc[5], acc[6], acc[7]};
    ((float4*)outf)[(size_t)n * 32 + fl * 2 + 0] = o0;
    ((float4*)outf)[(size_t)n * 32 + fl * 2 + 1] = o1;
  }
}

// -------- GEMM: hA(fp16) = relu(A[M,128] @ W[128,128]) -----------------------
__global__ __launch_bounds__(256) void gemm_relu_h(const float* __restrict__ A,
                                                   const float* __restrict__ W,
                                                   ushort* __restrict__ hA, int M) {
  __shared__ float sW[32][128];
  __shared__ float sA[64][36];
  const int tid = threadIdx.x;
  const int row0 = blockIdx.x * 64;
  const int rg = tid >> 4;
  const int cg = tid & 15;

  float4 acc[4][2];
#pragma unroll
  for (int i = 0; i < 4; ++i) {
    acc[i][0] = float4{0.f, 0.f, 0.f, 0.f};
    acc[i][1] = float4{0.f, 0.f, 0.f, 0.f};
  }

  for (int kt = 0; kt < 128; kt += 32) {
#pragma unroll
    for (int i = 0; i < 4; ++i) {
      int idx = i * 256 + tid;
      int r = idx >> 5, c4 = idx & 31;
      ((float4*)&sW[r][0])[c4] = ((const float4*)W)[(kt + r) * 32 + c4];
    }
#pragma unroll
    for (int i = 0; i < 2; ++i) {
      int idx = i * 256 + tid;
      int r = idx >> 3, c4 = idx & 7;
      int gr = row0 + r;
      float4 v = float4{0.f, 0.f, 0.f, 0.f};
      if (gr < M) v = ((const float4*)A)[gr * 32 + (kt >> 2) + c4];
      *(float4*)&sA[r][c4 * 4] = v;
    }
    __syncthreads();

#pragma unroll
    for (int k = 0; k < 32; k += 4) {
      float4 a0 = *(const float4*)&sA[rg * 4 + 0][k];
      float4 a1 = *(const float4*)&sA[rg * 4 + 1][k];
      float4 a2 = *(const float4*)&sA[rg * 4 + 2][k];
      float4 a3 = *(const float4*)&sA[rg * 4 + 3][k];
      const float* ap0 = (const float*)&a0;
      const float* ap1 = (const float*)&a1;
      const float* ap2 = (const float*)&a2;
      const float* ap3 = (const float*)&a3;
#pragma unroll
      for (int kk = 0; kk < 4; ++kk) {
        float4 w0 = *(const float4*)&sW[k + kk][cg * 8];
        float4 w1 = *(const float4*)&sW[k + kk][cg * 8 + 4];
        float a0k = ap0[kk], a1k = ap1[kk], a2k = ap2[kk], a3k = ap3[kk];
#define FMA_ROW(I, AK)                                                         \
        acc[I][0].x += AK * w0.x; acc[I][0].y += AK * w0.y;                    \
        acc[I][0].z += AK * w0.z; acc[I][0].w += AK * w0.w;                    \
        acc[I][1].x += AK * w1.x; acc[I][1].y += AK * w1.y;                    \
        acc[I][1].z += AK * w1.z; acc[I][1].w += AK * w1.w;
        FMA_ROW(0, a0k)
        FMA_ROW(1, a1k)
        FMA_ROW(2, a2k)
        FMA_ROW(3, a3k)
#undef FMA_ROW
      }
    }
    __syncthreads();
  }

#pragma unroll
  for (int i = 0; i < 4; ++i) {
    int gr = row0 + rg * 4 + i;
    if (gr < M) {
      float4 a0 = acc[i][0], a1 = acc[i][1];
      a0.x = fmaxf(a0.x, 0.f); a0.y = fmaxf(a0.y, 0.f);
      a0.z = fmaxf(a0.z, 0.f); a0.w = fmaxf(a0.w, 0.f);
      a1.x = fmaxf(a1.x, 0.f); a1.y = fmaxf(a1.y, 0.f);
      a1.z = fmaxf(a1.z, 0.f); a1.w = fmaxf(a1.w, 0.f);
      uint4 o;
      o.x = (uint)f2h(a0.x) | ((uint)f2h(a0.y) << 16);
      o.y = (uint)f2h(a0.z) | ((uint)f2h(a0.w) << 16);
      o.z = (uint)f2h(a1.x) | ((uint)f2h(a1.y) << 16);
      o.w = (uint)f2h(a1.z) | ((uint)f2h(a1.w) << 16);
      ((uint4*)hA)[gr * 16 + cg] = o;
    }
  }
}

// ------- pool: poolpart[s][g][:] = sum over nodes n of graph g (slice s) of
// sum_{slots} hA[col16[n][j]][:].  Register accumulation, no atomics.
__global__ __launch_bounds__(256) void pool_split(const ushort* __restrict__ hA,
                                                  const int* __restrict__ deg,
                                                  const ushort* __restrict__ col16,
                                                  const int* __restrict__ batch,
                                                  float* __restrict__ poolpart) {
  __shared__ float part[4][128];
  const int g = blockIdx.x;
  const int s = blockIdx.y;
  const int tid = threadIdx.x;
  const int wv = tid >> 6;
  const int lane = tid & 63;
  const int eg = lane >> 4;
  const int fl = lane & 15;

  int lo = 0, hi = N_NODES;
  while (lo < hi) { int m = (lo + hi) >> 1; if (batch[m] < g) lo = m + 1; else hi = m; }
  int s0 = lo;
  lo = 0; hi = N_NODES;
  while (lo < hi) { int m = (lo + hi) >> 1; if (batch[m] <= g) lo = m + 1; else hi = m; }
  int s1 = lo;

  float acc[8] = {0.f, 0.f, 0.f, 0.f, 0.f, 0.f, 0.f, 0.f};
  for (int n = s0 + s * 4 + wv; n < s1; n += NS * 4) {
    int dg = deg[n];
    const ushort* cp = col16 + (size_t)n * STRIDE;
    int j = eg;
    for (; j + 4 < dg; j += 8) {
      int a0 = cp[j], a1 = cp[j + 4];
      uint4 u0 = ((const uint4*)hA)[(size_t)a0 * 16 + fl];
      uint4 u1 = ((const uint4*)hA)[(size_t)a1 * 16 + fl];
      acc8(acc, u0);
      acc8(acc, u1);
    }
    if (j < dg) {
      uint4 u0 = ((const uint4*)hA)[(size_t)cp[j] * 16 + fl];
      acc8(acc, u0);
    }
  }

#pragma unroll
  for (int k = 0; k < 8; ++k) {
    acc[k] += __shfl_xor(acc[k], 16, 64);
    acc[k] += __shfl_xor(acc[k], 32, 64);
  }
  if (eg == 0) {
#pragma unroll
    for (int k = 0; k < 8; ++k) part[wv][fl * 8 + k] = acc[k];
  }
  __syncthreads();

  if (tid < 128) {
    float ss = part[0][tid] + part[1][tid] + part[2][tid] + part[3][tid];
    poolpart[((size_t)s * N_GRAPHS + g) * NF + tid] = ss;
  }
}

// ------- finish: z[g] = (sum_s poolpart[s][g] / cnt) . v ; sigmoid -----------
__global__ __launch_bounds__(128) void pool_finish(const float* __restrict__ poolpart,
                                                   const int* __restrict__ batch,
                                                   const float* __restrict__ v,
                                                   float* __restrict__ out) {
  __shared__ float reds[2];
  int g = blockIdx.x, f = threadIdx.x;

  int lo = 0, hi = N_NODES;
  while (lo < hi) { int m = (lo + hi) >> 1; if (batch[m] < g) lo = m + 1; else hi = m; }
  int s0 = lo;
  lo = 0; hi = N_NODES;
  while (lo < hi) { int m = (lo + hi) >> 1; if (batch[m] <= g) lo = m + 1; else hi = m; }
  int s1 = lo;

  float ss = 0.f;
#pragma unroll
  for (int i = 0; i < NS; ++i)
    ss += poolpart[((size_t)i * N_GRAPHS + g) * NF + f];

  float cnt = fmaxf((float)(s1 - s0), 1.0f);
  float z = (ss / cnt) * v[f];
#pragma unroll
  for (int off = 32; off > 0; off >>= 1) z += __shfl_down(z, off, 64);
  if (f == 0) reds[0] = z;
  if (f == 64) reds[1] = z;
  __syncthreads();
  if (f == 0) {
    float zz = reds[0] + reds[1];
    out[g] = 1.0f / (1.0f + expf(-zz));
  }
}

extern "C" void kernel_launch(void* const* d_in, const int* in_sizes, int n_in,
                              void* d_out, int out_size, void* d_ws, size_t ws_size,
                              hipStream_t stream) {
  const float* x   = (const float*)d_in[0];
  const int*   ei  = (const int*)d_in[1];
  const int*   src = ei;               // edge_index[0]
  const int*   dst = ei + N_EDGES;     // edge_index[1]
  const int* batch = (const int*)d_in[2];
  const float* W1  = (const float*)d_in[3];
  const float* W2  = (const float*)d_in[4];
  const float* Wfc = (const float*)d_in[5];
  float* out = (float*)d_out;

  // bufA (agg_x, f32) is dead until gather_x runs, so the CSR-build scratch
  // (ebuf / bhist / R / blocksum) aliases its space.
  float*  bufA = (float*)d_ws;                           // 6.4M f32
  uint*   ebuf = (uint*)d_ws;                            // 800000 u32 (alias)
  int*    bhist = (int*)(ebuf + N_EDGES);                // SC_N       (alias)
  int*    R     = bhist + SC_N;                          // SC_N+1     (alias)
  int*    blocksum = R + SC_N + 1;                       // SC_BLOCKS  (alias)

  ushort* xh   = (ushort*)(bufA + (size_t)N_NODES * NF); // 6.4M fp16
  ushort* hA   = xh + (size_t)N_NODES * NF;              // 6.4M fp16
  ushort* col16 = hA + (size_t)N_NODES * NF;             // 50000*64 ushort
  float* poolpart = (float*)(col16 + (size_t)N_NODES * STRIDE); // NS*512*128
  int* deg     = (int*)(poolpart + (size_t)NS * N_GRAPHS * NF); // 50000
  float* v     = (float*)(deg + N_NODES);                // 128

  const int gemm_grid = (N_NODES + 63) / 64;            // 782
  const int cvt_grid  = (N_NODES * NF / 4) / 256;       // 6250 exact
  const int gath_grid = (N_NODES * 64 + 255) / 256;     // 12500
  const int st3_grid  = (SC_N + 255) / 256;             // 300

  // --- build CSR: bin by dst>>7, then per-bin single-block fill ---
  bin_count<<<NBLK, 256, 0, stream>>>(dst, bhist);
  scan_stage1<<<SC_BLOCKS, 256, 0, stream>>>(bhist, R, blocksum);
  scan_stage2<<<1, 256, 0, stream>>>(blocksum);
  scan_stage3<<<st3_grid, 256, 0, stream>>>(R, blocksum);
  bin_scatter<<<NBLK, 256, 0, stream>>>(src, dst, R, ebuf);
  csr_from_bins<<<NBINS, 256, 0, stream>>>(ebuf, R, deg, col16);

  // --- precompute fp16 x and v = W2@Wfc ---
  xcvt<<<cvt_grid, 256, 0, stream>>>(x, xh);
  w2wfc<<<1, 128, 0, stream>>>(W2, Wfc, v);

  // --- conv1: agg_x = gather(xh); hA = relu(agg_x @ W1) (fp16) ---
  gather_x<<<gath_grid, 256, 0, stream>>>(xh, deg, col16, bufA);
  gemm_relu_h<<<gemm_grid, 256, 0, stream>>>(bufA, W1, hA, N_NODES);

  // --- conv2-agg + pool: per-(graph,slice) register accumulation ---
  pool_split<<<dim3(N_GRAPHS, NS), 256, 0, stream>>>(hA, deg, col16, batch,
                                                     poolpart);
  pool_finish<<<N_GRAPHS, 128, 0, stream>>>(poolpart, batch, v, out);
}

// Round 10
// 118.944 us; speedup vs baseline: 1.8988x; 1.3263x over previous
//
#include <hip/hip_runtime.h>

#define N_NODES 50000
#define N_EDGES 800000
#define NF 128
#define N_GRAPHS 512
#define STRIDE 64        // fixed CSR slots/node; P(deg>64) ~ 1e-13 for Poisson(16)

#define NBINS 391        // ceil(50000/128) bins of 128 nodes (dst>>7)
#define NBLK 196         // edge blocks: ceil(800000/4096)
#define EPB 4096         // edges per block in binning passes
#define SC_N (NBINS * NBLK)   // 76636 scan elements
#define SC_BLOCKS 38     // ceil(SC_N/2048)

union HU { ushort u; _Float16 h; };
__device__ __forceinline__ float h2f(ushort u) { HU x; x.u = u; return (float)x.h; }
__device__ __forceinline__ ushort f2h(float f) { HU x; x.h = (_Float16)f; return x.u; }

__device__ __forceinline__ void acc8(float* acc, uint4 u) {
  acc[0] += h2f((ushort)(u.x)); acc[1] += h2f((ushort)(u.x >> 16));
  acc[2] += h2f((ushort)(u.y)); acc[3] += h2f((ushort)(u.y >> 16));
  acc[4] += h2f((ushort)(u.z)); acc[5] += h2f((ushort)(u.z >> 16));
  acc[6] += h2f((ushort)(u.w)); acc[7] += h2f((ushort)(u.w >> 16));
}

// ---------------- x (f32) -> xh (fp16) ---------------------------------------
__global__ __launch_bounds__(256) void xcvt(const float* __restrict__ x,
                                            ushort* __restrict__ xh) {
  int i = blockIdx.x * 256 + threadIdx.x;
  float4 v = ((const float4*)x)[i];
  ushort4 o;
  o.x = f2h(v.x); o.y = f2h(v.y); o.z = f2h(v.z); o.w = f2h(v.w);
  ((ushort4*)xh)[i] = o;
}

// ---------------- v[f] = sum_j W2[f][j] * Wfc[j] ------------------------------
__global__ __launch_bounds__(128) void w2wfc(const float* __restrict__ W2,
                                             const float* __restrict__ Wfc,
                                             float* __restrict__ v) {
  int f = threadIdx.x;
  float s = 0.f;
  for (int j = 0; j < 128; j += 4) {
    float4 w = ((const float4*)(W2 + f * 128))[j >> 2];
    float4 c = ((const float4*)Wfc)[j >> 2];
    s += w.x * c.x + w.y * c.y + w.z * c.z + w.w * c.w;
  }
  v[f] = s;
}

// ======== CSR build, phase A: bin edges by dst>>7 (128-node bins) ============
__global__ __launch_bounds__(256) void bin_count(const int* __restrict__ dst,
                                                 int* __restrict__ bhist) {
  __shared__ int hist[NBINS];
  for (int i = threadIdx.x; i < NBINS; i += 256) hist[i] = 0;
  __syncthreads();
  int e0 = blockIdx.x * EPB;
  int e1 = e0 + EPB; if (e1 > N_EDGES) e1 = N_EDGES;
  for (int e = e0 + threadIdx.x; e < e1; e += 256)
    atomicAdd(&hist[dst[e] >> 7], 1);
  __syncthreads();
  for (int i = threadIdx.x; i < NBINS; i += 256)
    bhist[i * NBLK + blockIdx.x] = hist[i];
}

__device__ __forceinline__ int block_incl_scan_256(int v, int* warp_sums) {
  const int tid = threadIdx.x;
  const int lane = tid & 63;
  const int w = tid >> 6;
#pragma unroll
  for (int off = 1; off < 64; off <<= 1) {
    int t = __shfl_up(v, off, 64);
    if (lane >= off) v += t;
  }
  if (lane == 63) warp_sums[w] = v;
  __syncthreads();
  int ws = 0;
#pragma unroll
  for (int i = 0; i < 4; ++i) ws += (i < w) ? warp_sums[i] : 0;
  return v + ws;
}

__global__ __launch_bounds__(256) void scan_stage1(const int* __restrict__ in,
                                                   int* __restrict__ R,
                                                   int* __restrict__ blocksum) {
  __shared__ int warp_sums[4];
  int tid = threadIdx.x;
  int i0 = blockIdx.x * 2048 + tid * 8;
  int v[8];
  int s = 0;
#pragma unroll
  for (int k = 0; k < 8; ++k) {
    int idx = i0 + k;
    v[k] = (idx < SC_N) ? in[idx] : 0;
    s += v[k];
  }
  int incl = block_incl_scan_256(s, warp_sums);
  int run = incl - s;
#pragma unroll
  for (int k = 0; k < 8; ++k) {
    run += v[k];
    int idx = i0 + k;
    if (idx < SC_N) R[idx + 1] = run;
  }
  if (tid == 255) blocksum[blockIdx.x] = incl;
}

__global__ __launch_bounds__(256) void scan_stage2(int* __restrict__ blocksum) {
  __shared__ int warp_sums[4];
  int tid = threadIdx.x;
  int v = (tid < SC_BLOCKS) ? blocksum[tid] : 0;
  int incl = block_incl_scan_256(v, warp_sums);
  if (tid < SC_BLOCKS) blocksum[tid] = incl - v;
}

__global__ __launch_bounds__(256) void scan_stage3(int* __restrict__ R,
                                                   const int* __restrict__ blocksum) {
  int i = blockIdx.x * 256 + threadIdx.x;
  if (i < SC_N) R[i + 1] += blocksum[i >> 11];
  if (i == 0) R[0] = 0;
}

__global__ __launch_bounds__(256) void bin_scatter(const int* __restrict__ src,
                                                   const int* __restrict__ dst,
                                                   const int* __restrict__ R,
                                                   uint* __restrict__ ebuf) {
  __shared__ int cur[NBINS];
  for (int i = threadIdx.x; i < NBINS; i += 256) cur[i] = 0;
  __syncthreads();
  int e0 = blockIdx.x * EPB;
  int e1 = e0 + EPB; if (e1 > N_EDGES) e1 = N_EDGES;
  for (int e = e0 + threadIdx.x; e < e1; e += 256) {
    int d = dst[e];
    int b = d >> 7;
    int loc = atomicAdd(&cur[b], 1);
    ebuf[R[b * NBLK + blockIdx.x] + loc] = ((uint)d << 16) | (uint)src[e];
  }
}

// ======== CSR build, phase B: one block per bin -> col16 window + deg ========
__global__ __launch_bounds__(256) void csr_from_bins(const uint* __restrict__ ebuf,
                                                     const int* __restrict__ R,
                                                     int* __restrict__ deg,
                                                     ushort* __restrict__ col16) {
  __shared__ int dl[128];
  const int bin = blockIdx.x;
  const int n0 = bin << 7;
  if (threadIdx.x < 128) dl[threadIdx.x] = 0;
  __syncthreads();
  int j0 = R[bin * NBLK];
  int j1 = R[(bin + 1) * NBLK];
  for (int j = j0 + threadIdx.x; j < j1; j += 256) {
    uint e = ebuf[j];
    int d = (int)(e >> 16);
    int slot = atomicAdd(&dl[d - n0], 1);
    col16[(size_t)d * STRIDE + slot] = (ushort)(e & 0xFFFFu);
  }
  __syncthreads();
  int cnt = N_NODES - n0; if (cnt > 128) cnt = 128;
  if (threadIdx.x < cnt) deg[n0 + threadIdx.x] = dl[threadIdx.x];
}

// ------- gather1: agg_x[n][:] = sum_{slots} xh[col16[n][s]][:]  (f32 out) ----
__global__ __launch_bounds__(256) void gather_x(const ushort* __restrict__ xh,
                                                const int* __restrict__ deg,
                                                const ushort* __restrict__ col16,
                                                float* __restrict__ outf) {
  int n = (blockIdx.x * 256 + threadIdx.x) >> 6;
  if (n >= N_NODES) return;
  const int lane = threadIdx.x & 63;
  const int eg = lane >> 4;    // 0..3 edge group
  const int fl = lane & 15;    // feat lane: 8 fp16 = 16B

  int dg = deg[n];
  const ushort* cp = col16 + (size_t)n * STRIDE;
  float acc[8] = {0.f, 0.f, 0.f, 0.f, 0.f, 0.f, 0.f, 0.f};

  int j = eg;
  for (; j + 4 < dg; j += 8) {
    int s0 = cp[j], s1 = cp[j + 4];
    uint4 a = ((const uint4*)xh)[(size_t)s0 * 16 + fl];
    uint4 b = ((const uint4*)xh)[(size_t)s1 * 16 + fl];
    acc8(acc, a);
    acc8(acc, b);
  }
  if (j < dg) {
    uint4 a = ((const uint4*)xh)[(size_t)cp[j] * 16 + fl];
    acc8(acc, a);
  }

#pragma unroll
  for (int k = 0; k < 8; ++k) {
    acc[k] += __shfl_xor(acc[k], 16, 64);
    acc[k] += __shfl_xor(acc[k], 32, 64);
  }
  if (eg == 0) {
    float4 o0 = {acc[0], acc[1], acc[2], acc[3]};
    float4 o1 = {acc[4], acc[5], acc[6], acc[7]};
    ((float4*)outf)[(size_t)n * 32 + fl * 2 + 0] = o0;
    ((float4*)outf)[(size_t)n * 32 + fl * 2 + 1] = o1;
  }
}

// -------- GEMM + epilogue collapse: q[m] = relu(A[m]@W1) . v -----------------
// conv2+pool only ever consume h1 through dot with v = W2@Wfc, so emit the
// scalar q per node instead of the 128-wide h1 (kills the hA buffer).
__global__ __launch_bounds__(256) void gemm_relu_qdot(const float* __restrict__ A,
                                                      const float* __restrict__ W,
                                                      const float* __restrict__ vq,
                                                      float* __restrict__ q, int M) {
  __shared__ float sW[32][128];
  __shared__ float sA[64][36];
  const int tid = threadIdx.x;
  const int row0 = blockIdx.x * 64;
  const int rg = tid >> 4;
  const int cg = tid & 15;

  float4 acc[4][2];
#pragma unroll
  for (int i = 0; i < 4; ++i) {
    acc[i][0] = float4{0.f, 0.f, 0.f, 0.f};
    acc[i][1] = float4{0.f, 0.f, 0.f, 0.f};
  }

  for (int kt = 0; kt < 128; kt += 32) {
#pragma unroll
    for (int i = 0; i < 4; ++i) {
      int idx = i * 256 + tid;
      int r = idx >> 5, c4 = idx & 31;
      ((float4*)&sW[r][0])[c4] = ((const float4*)W)[(kt + r) * 32 + c4];
    }
#pragma unroll
    for (int i = 0; i < 2; ++i) {
      int idx = i * 256 + tid;
      int r = idx >> 3, c4 = idx & 7;
      int gr = row0 + r;
      float4 v = float4{0.f, 0.f, 0.f, 0.f};
      if (gr < M) v = ((const float4*)A)[gr * 32 + (kt >> 2) + c4];
      *(float4*)&sA[r][c4 * 4] = v;
    }
    __syncthreads();

#pragma unroll
    for (int k = 0; k < 32; k += 4) {
      float4 a0 = *(const float4*)&sA[rg * 4 + 0][k];
      float4 a1 = *(const float4*)&sA[rg * 4 + 1][k];
      float4 a2 = *(const float4*)&sA[rg * 4 + 2][k];
      float4 a3 = *(const float4*)&sA[rg * 4 + 3][k];
      const float* ap0 = (const float*)&a0;
      const float* ap1 = (const float*)&a1;
      const float* ap2 = (const float*)&a2;
      const float* ap3 = (const float*)&a3;
#pragma unroll
      for (int kk = 0; kk < 4; ++kk) {
        float4 w0 = *(const float4*)&sW[k + kk][cg * 8];
        float4 w1 = *(const float4*)&sW[k + kk][cg * 8 + 4];
        float a0k = ap0[kk], a1k = ap1[kk], a2k = ap2[kk], a3k = ap3[kk];
#define FMA_ROW(I, AK)                                                         \
        acc[I][0].x += AK * w0.x; acc[I][0].y += AK * w0.y;                    \
        acc[I][0].z += AK * w0.z; acc[I][0].w += AK * w0.w;                    \
        acc[I][1].x += AK * w1.x; acc[I][1].y += AK * w1.y;                    \
        acc[I][1].z += AK * w1.z; acc[I][1].w += AK * w1.w;
        FMA_ROW(0, a0k)
        FMA_ROW(1, a1k)
        FMA_ROW(2, a2k)
        FMA_ROW(3, a3k)
#undef FMA_ROW
      }
    }
    __syncthreads();
  }

  // epilogue: per-row relu + dot with v, reduced across the 16 cg lanes
  float4 v0 = ((const float4*)vq)[cg * 2];
  float4 v1 = ((const float4*)vq)[cg * 2 + 1];
#pragma unroll
  for (int i = 0; i < 4; ++i) {
    int gr = row0 + rg * 4 + i;
    float4 a0 = acc[i][0], a1 = acc[i][1];
    float p = fmaxf(a0.x, 0.f) * v0.x + fmaxf(a0.y, 0.f) * v0.y +
              fmaxf(a0.z, 0.f) * v0.z + fmaxf(a0.w, 0.f) * v0.w +
              fmaxf(a1.x, 0.f) * v1.x + fmaxf(a1.y, 0.f) * v1.y +
              fmaxf(a1.z, 0.f) * v1.z + fmaxf(a1.w, 0.f) * v1.w;
    p += __shfl_xor(p, 1, 64);
    p += __shfl_xor(p, 2, 64);
    p += __shfl_xor(p, 4, 64);
    p += __shfl_xor(p, 8, 64);
    if (cg == 0 && gr < M) q[gr] = p;
  }
}

// ------- pool: out[g] = sigmoid( (sum over graph-g edges of q[src]) / cnt ) --
// q is 200KB -> L2-resident; scalar gather per edge. One block per graph.
__global__ __launch_bounds__(256) void pool_q(const float* __restrict__ q,
                                              const int* __restrict__ deg,
                                              const ushort* __restrict__ col16,
                                              const int* __restrict__ batch,
                                              float* __restrict__ out) {
  __shared__ float red[4];
  int g = blockIdx.x, tid = threadIdx.x;

  int lo = 0, hi = N_NODES;
  while (lo < hi) { int m = (lo + hi) >> 1; if (batch[m] < g) lo = m + 1; else hi = m; }
  int s0 = lo;
  lo = 0; hi = N_NODES;
  while (lo < hi) { int m = (lo + hi) >> 1; if (batch[m] <= g) lo = m + 1; else hi = m; }
  int s1 = lo;

  float sum = 0.f;
  for (int n = s0 + (tid >> 3); n < s1; n += 32) {
    int dg = deg[n];
    const ushort* cp = col16 + (size_t)n * STRIDE;
    for (int j = tid & 7; j < dg; j += 8) sum += q[cp[j]];
  }
#pragma unroll
  for (int off = 32; off > 0; off >>= 1) sum += __shfl_down(sum, off, 64);
  if ((tid & 63) == 0) red[tid >> 6] = sum;
  __syncthreads();
  if (tid == 0) {
    float z = red[0] + red[1] + red[2] + red[3];
    float cnt = fmaxf((float)(s1 - s0), 1.0f);
    z /= cnt;
    out[g] = 1.0f / (1.0f + expf(-z));
  }
}

extern "C" void kernel_launch(void* const* d_in, const int* in_sizes, int n_in,
                              void* d_out, int out_size, void* d_ws, size_t ws_size,
                              hipStream_t stream) {
  const float* x   = (const float*)d_in[0];
  const int*   ei  = (const int*)d_in[1];
  const int*   src = ei;               // edge_index[0]
  const int*   dst = ei + N_EDGES;     // edge_index[1]
  const int* batch = (const int*)d_in[2];
  const float* W1  = (const float*)d_in[3];
  const float* W2  = (const float*)d_in[4];
  const float* Wfc = (const float*)d_in[5];
  float* out = (float*)d_out;

  // bufA (agg_x, f32) is dead until gather_x runs, so the CSR-build scratch
  // (ebuf / bhist / R / blocksum) aliases its space.
  float*  bufA = (float*)d_ws;                           // 6.4M f32
  uint*   ebuf = (uint*)d_ws;                            // 800000 u32 (alias)
  int*    bhist = (int*)(ebuf + N_EDGES);                // SC_N       (alias)
  int*    R     = bhist + SC_N;                          // SC_N+1     (alias)
  int*    blocksum = R + SC_N + 1;                       // SC_BLOCKS  (alias)

  ushort* xh   = (ushort*)(bufA + (size_t)N_NODES * NF); // 6.4M fp16
  ushort* col16 = xh + (size_t)N_NODES * NF;             // 50000*64 ushort
  int* deg     = (int*)(col16 + (size_t)N_NODES * STRIDE); // 50000
  float* q     = (float*)(deg + N_NODES);                // 50000
  float* v     = q + N_NODES;                            // 128

  const int gemm_grid = (N_NODES + 63) / 64;            // 782
  const int cvt_grid  = (N_NODES * NF / 4) / 256;       // 6250 exact
  const int gath_grid = (N_NODES * 64 + 255) / 256;     // 12500
  const int st3_grid  = (SC_N + 255) / 256;             // 300

  // --- build CSR: bin by dst>>7, then per-bin single-block fill ---
  bin_count<<<NBLK, 256, 0, stream>>>(dst, bhist);
  scan_stage1<<<SC_BLOCKS, 256, 0, stream>>>(bhist, R, blocksum);
  scan_stage2<<<1, 256, 0, stream>>>(blocksum);
  scan_stage3<<<st3_grid, 256, 0, stream>>>(R, blocksum);
  bin_scatter<<<NBLK, 256, 0, stream>>>(src, dst, R, ebuf);
  csr_from_bins<<<NBINS, 256, 0, stream>>>(ebuf, R, deg, col16);

  // --- precompute fp16 x and v = W2@Wfc ---
  xcvt<<<cvt_grid, 256, 0, stream>>>(x, xh);
  w2wfc<<<1, 128, 0, stream>>>(W2, Wfc, v);

  // --- conv1: agg_x = gather(xh); q = relu(agg_x @ W1) . v  (per node) ---
  gather_x<<<gath_grid, 256, 0, stream>>>(xh, deg, col16, bufA);
  gemm_relu_qdot<<<gemm_grid, 256, 0, stream>>>(bufA, W1, v, q, N_NODES);

  // --- conv2 + pool + fc + sigmoid: scalar gather over L2-resident q ---
  pool_q<<<N_GRAPHS, 256, 0, stream>>>(q, deg, col16, batch, out);
}

// Round 11
// 112.374 us; speedup vs baseline: 2.0098x; 1.0585x over previous
//
#include <hip/hip_runtime.h>

#define N_NODES 50000
#define N_EDGES 800000
#define NF 128
#define N_GRAPHS 512
#define STRIDE 64        // fixed CSR slots/node; P(deg>64) ~ 1e-13 for Poisson(16)

#define NBINS 391        // ceil(50000/128) bins of 128 nodes (dst>>7)
#define NBLK 196         // edge blocks: ceil(800000/4096)
#define EPB 4096         // edges per block in binning passes
#define SC_N (NBINS * NBLK)   // 76636 scan elements
#define SC_BLOCKS 38     // ceil(SC_N/2048)

union HU { ushort u; _Float16 h; };
__device__ __forceinline__ float h2f(ushort u) { HU x; x.u = u; return (float)x.h; }
__device__ __forceinline__ ushort f2h(float f) { HU x; x.h = (_Float16)f; return x.u; }

__device__ __forceinline__ void acc8(float* acc, uint4 u) {
  acc[0] += h2f((ushort)(u.x)); acc[1] += h2f((ushort)(u.x >> 16));
  acc[2] += h2f((ushort)(u.y)); acc[3] += h2f((ushort)(u.y >> 16));
  acc[4] += h2f((ushort)(u.z)); acc[5] += h2f((ushort)(u.z >> 16));
  acc[6] += h2f((ushort)(u.w)); acc[7] += h2f((ushort)(u.w >> 16));
}

// ---------------- v[f] = sum_j W2[f][j] * Wfc[j] ------------------------------
__global__ __launch_bounds__(128) void w2wfc(const float* __restrict__ W2,
                                             const float* __restrict__ Wfc,
                                             float* __restrict__ v) {
  int f = threadIdx.x;
  float s = 0.f;
  for (int j = 0; j < 128; j += 4) {
    float4 w = ((const float4*)(W2 + f * 128))[j >> 2];
    float4 c = ((const float4*)Wfc)[j >> 2];
    s += w.x * c.x + w.y * c.y + w.z * c.z + w.w * c.w;
  }
  v[f] = s;
}

// ======== CSR build, phase A: bin edges by dst>>7 (128-node bins) ============
__global__ __launch_bounds__(256) void bin_count(const int* __restrict__ dst,
                                                 int* __restrict__ bhist) {
  __shared__ int hist[NBINS];
  for (int i = threadIdx.x; i < NBINS; i += 256) hist[i] = 0;
  __syncthreads();
  int e0 = blockIdx.x * EPB;
  int e1 = e0 + EPB; if (e1 > N_EDGES) e1 = N_EDGES;
  for (int e = e0 + threadIdx.x; e < e1; e += 256)
    atomicAdd(&hist[dst[e] >> 7], 1);
  __syncthreads();
  for (int i = threadIdx.x; i < NBINS; i += 256)
    bhist[i * NBLK + blockIdx.x] = hist[i];
}

__device__ __forceinline__ int block_incl_scan_256(int v, int* warp_sums) {
  const int tid = threadIdx.x;
  const int lane = tid & 63;
  const int w = tid >> 6;
#pragma unroll
  for (int off = 1; off < 64; off <<= 1) {
    int t = __shfl_up(v, off, 64);
    if (lane >= off) v += t;
  }
  if (lane == 63) warp_sums[w] = v;
  __syncthreads();
  int ws = 0;
#pragma unroll
  for (int i = 0; i < 4; ++i) ws += (i < w) ? warp_sums[i] : 0;
  return v + ws;
}

__global__ __launch_bounds__(256) void scan_stage1(const int* __restrict__ in,
                                                   int* __restrict__ R,
                                                   int* __restrict__ blocksum) {
  __shared__ int warp_sums[4];
  int tid = threadIdx.x;
  int i0 = blockIdx.x * 2048 + tid * 8;
  int v[8];
  int s = 0;
#pragma unroll
  for (int k = 0; k < 8; ++k) {
    int idx = i0 + k;
    v[k] = (idx < SC_N) ? in[idx] : 0;
    s += v[k];
  }
  int incl = block_incl_scan_256(s, warp_sums);
  int run = incl - s;
#pragma unroll
  for (int k = 0; k < 8; ++k) {
    run += v[k];
    int idx = i0 + k;
    if (idx < SC_N) R[idx + 1] = run;
  }
  if (tid == 255) blocksum[blockIdx.x] = incl;
}

__global__ __launch_bounds__(256) void scan_stage2(int* __restrict__ blocksum) {
  __shared__ int warp_sums[4];
  int tid = threadIdx.x;
  int v = (tid < SC_BLOCKS) ? blocksum[tid] : 0;
  int incl = block_incl_scan_256(v, warp_sums);
  if (tid < SC_BLOCKS) blocksum[tid] = incl - v;
}

__global__ __launch_bounds__(256) void scan_stage3(int* __restrict__ R,
                                                   const int* __restrict__ blocksum) {
  int i = blockIdx.x * 256 + threadIdx.x;
  if (i < SC_N) R[i + 1] += blocksum[i >> 11];
  if (i == 0) R[0] = 0;
}

__global__ __launch_bounds__(256) void bin_scatter(const int* __restrict__ src,
                                                   const int* __restrict__ dst,
                                                   const int* __restrict__ R,
                                                   uint* __restrict__ ebuf) {
  __shared__ int cur[NBINS];
  for (int i = threadIdx.x; i < NBINS; i += 256) cur[i] = 0;
  __syncthreads();
  int e0 = blockIdx.x * EPB;
  int e1 = e0 + EPB; if (e1 > N_EDGES) e1 = N_EDGES;
  for (int e = e0 + threadIdx.x; e < e1; e += 256) {
    int d = dst[e];
    int b = d >> 7;
    int loc = atomicAdd(&cur[b], 1);
    ebuf[R[b * NBLK + blockIdx.x] + loc] = ((uint)d << 16) | (uint)src[e];
  }
}

// ======== CSR build, phase B: one block per bin -> col16 window + deg ========
__global__ __launch_bounds__(256) void csr_from_bins(const uint* __restrict__ ebuf,
                                                     const int* __restrict__ R,
                                                     int* __restrict__ deg,
                                                     ushort* __restrict__ col16) {
  __shared__ int dl[128];
  const int bin = blockIdx.x;
  const int n0 = bin << 7;
  if (threadIdx.x < 128) dl[threadIdx.x] = 0;
  __syncthreads();
  int j0 = R[bin * NBLK];
  int j1 = R[(bin + 1) * NBLK];
  for (int j = j0 + threadIdx.x; j < j1; j += 256) {
    uint e = ebuf[j];
    int d = (int)(e >> 16);
    int slot = atomicAdd(&dl[d - n0], 1);
    col16[(size_t)d * STRIDE + slot] = (ushort)(e & 0xFFFFu);
  }
  __syncthreads();
  int cnt = N_NODES - n0; if (cnt > 128) cnt = 128;
  if (threadIdx.x < cnt) deg[n0 + threadIdx.x] = dl[threadIdx.x];
}

// -------- GEMM: y16 = x @ W1 (fp16, no relu) ---------------------------------
// gather(x) @ W1 == gather(x @ W1), so the dense GEMM runs on x directly and
// the gather consumes the fp16 product rows.
__global__ __launch_bounds__(256) void gemm_h16(const float* __restrict__ A,
                                                const float* __restrict__ W,
                                                ushort* __restrict__ y16, int M) {
  __shared__ float sW[32][128];
  __shared__ float sA[64][36];
  const int tid = threadIdx.x;
  const int row0 = blockIdx.x * 64;
  const int rg = tid >> 4;
  const int cg = tid & 15;

  float4 acc[4][2];
#pragma unroll
  for (int i = 0; i < 4; ++i) {
    acc[i][0] = float4{0.f, 0.f, 0.f, 0.f};
    acc[i][1] = float4{0.f, 0.f, 0.f, 0.f};
  }

  for (int kt = 0; kt < 128; kt += 32) {
#pragma unroll
    for (int i = 0; i < 4; ++i) {
      int idx = i * 256 + tid;
      int r = idx >> 5, c4 = idx & 31;
      ((float4*)&sW[r][0])[c4] = ((const float4*)W)[(kt + r) * 32 + c4];
    }
#pragma unroll
    for (int i = 0; i < 2; ++i) {
      int idx = i * 256 + tid;
      int r = idx >> 3, c4 = idx & 7;
      int gr = row0 + r;
      float4 v = float4{0.f, 0.f, 0.f, 0.f};
      if (gr < M) v = ((const float4*)A)[gr * 32 + (kt >> 2) + c4];
      *(float4*)&sA[r][c4 * 4] = v;
    }
    __syncthreads();

#pragma unroll
    for (int k = 0; k < 32; k += 4) {
      float4 a0 = *(const float4*)&sA[rg * 4 + 0][k];
      float4 a1 = *(const float4*)&sA[rg * 4 + 1][k];
      float4 a2 = *(const float4*)&sA[rg * 4 + 2][k];
      float4 a3 = *(const float4*)&sA[rg * 4 + 3][k];
      const float* ap0 = (const float*)&a0;
      const float* ap1 = (const float*)&a1;
      const float* ap2 = (const float*)&a2;
      const float* ap3 = (const float*)&a3;
#pragma unroll
      for (int kk = 0; kk < 4; ++kk) {
        float4 w0 = *(const float4*)&sW[k + kk][cg * 8];
        float4 w1 = *(const float4*)&sW[k + kk][cg * 8 + 4];
        float a0k = ap0[kk], a1k = ap1[kk], a2k = ap2[kk], a3k = ap3[kk];
#define FMA_ROW(I, AK)                                                         \
        acc[I][0].x += AK * w0.x; acc[I][0].y += AK * w0.y;                    \
        acc[I][0].z += AK * w0.z; acc[I][0].w += AK * w0.w;                    \
        acc[I][1].x += AK * w1.x; acc[I][1].y += AK * w1.y;                    \
        acc[I][1].z += AK * w1.z; acc[I][1].w += AK * w1.w;
        FMA_ROW(0, a0k)
        FMA_ROW(1, a1k)
        FMA_ROW(2, a2k)
        FMA_ROW(3, a3k)
#undef FMA_ROW
      }
    }
    __syncthreads();
  }

#pragma unroll
  for (int i = 0; i < 4; ++i) {
    int gr = row0 + rg * 4 + i;
    if (gr < M) {
      float4 a0 = acc[i][0], a1 = acc[i][1];
      uint4 o;
      o.x = (uint)f2h(a0.x) | ((uint)f2h(a0.y) << 16);
      o.y = (uint)f2h(a0.z) | ((uint)f2h(a0.w) << 16);
      o.z = (uint)f2h(a1.x) | ((uint)f2h(a1.y) << 16);
      o.w = (uint)f2h(a1.z) | ((uint)f2h(a1.w) << 16);
      ((uint4*)y16)[gr * 16 + cg] = o;
    }
  }
}

// ------- gather + relu + dot: q[n] = relu( sum_slots y16[col16[n][j]] ) . v --
// One node per wave64: 4 edge-groups x 16 feat-lanes (uint4 = 8 fp16).
// Epilogue reduces eg groups, then dots with v across the 16 fl lanes.
__global__ __launch_bounds__(256) void gather_qdot(const ushort* __restrict__ y16,
                                                   const int* __restrict__ deg,
                                                   const ushort* __restrict__ col16,
                                                   const float* __restrict__ vq,
                                                   float* __restrict__ q) {
  int n = (blockIdx.x * 256 + threadIdx.x) >> 6;
  if (n >= N_NODES) return;
  const int lane = threadIdx.x & 63;
  const int eg = lane >> 4;    // 0..3 edge group
  const int fl = lane & 15;    // feat lane: 8 fp16 = 16B

  int dg = deg[n];
  const ushort* cp = col16 + (size_t)n * STRIDE;
  float acc[8] = {0.f, 0.f, 0.f, 0.f, 0.f, 0.f, 0.f, 0.f};

  int j = eg;
  for (; j + 4 < dg; j += 8) {
    int s0 = cp[j], s1 = cp[j + 4];
    uint4 a = ((const uint4*)y16)[(size_t)s0 * 16 + fl];
    uint4 b = ((const uint4*)y16)[(size_t)s1 * 16 + fl];
    acc8(acc, a);
    acc8(acc, b);
  }
  if (j < dg) {
    uint4 a = ((const uint4*)y16)[(size_t)cp[j] * 16 + fl];
    acc8(acc, a);
  }

  // reduce the 4 edge groups
#pragma unroll
  for (int k = 0; k < 8; ++k) {
    acc[k] += __shfl_xor(acc[k], 16, 64);
    acc[k] += __shfl_xor(acc[k], 32, 64);
  }
  // relu + dot with v (each fl lane owns feats fl*8..fl*8+7)
  float4 v0 = ((const float4*)vq)[fl * 2];
  float4 v1 = ((const float4*)vq)[fl * 2 + 1];
  float p = fmaxf(acc[0], 0.f) * v0.x + fmaxf(acc[1], 0.f) * v0.y +
            fmaxf(acc[2], 0.f) * v0.z + fmaxf(acc[3], 0.f) * v0.w +
            fmaxf(acc[4], 0.f) * v1.x + fmaxf(acc[5], 0.f) * v1.y +
            fmaxf(acc[6], 0.f) * v1.z + fmaxf(acc[7], 0.f) * v1.w;
  // reduce across the 16 fl lanes (within eg==0 quarter)
  p += __shfl_xor(p, 1, 64);
  p += __shfl_xor(p, 2, 64);
  p += __shfl_xor(p, 4, 64);
  p += __shfl_xor(p, 8, 64);
  if (lane == 0) q[n] = p;
}

// ------- pool: out[g] = sigmoid( (sum over graph-g edges of q[src]) / cnt ) --
__global__ __launch_bounds__(256) void pool_q(const float* __restrict__ q,
                                              const int* __restrict__ deg,
                                              const ushort* __restrict__ col16,
                                              const int* __restrict__ batch,
                                              float* __restrict__ out) {
  __shared__ float red[4];
  int g = blockIdx.x, tid = threadIdx.x;

  int lo = 0, hi = N_NODES;
  while (lo < hi) { int m = (lo + hi) >> 1; if (batch[m] < g) lo = m + 1; else hi = m; }
  int s0 = lo;
  lo = 0; hi = N_NODES;
  while (lo < hi) { int m = (lo + hi) >> 1; if (batch[m] <= g) lo = m + 1; else hi = m; }
  int s1 = lo;

  float sum = 0.f;
  for (int n = s0 + (tid >> 3); n < s1; n += 32) {
    int dg = deg[n];
    const ushort* cp = col16 + (size_t)n * STRIDE;
    for (int j = tid & 7; j < dg; j += 8) sum += q[cp[j]];
  }
#pragma unroll
  for (int off = 32; off > 0; off >>= 1) sum += __shfl_down(sum, off, 64);
  if ((tid & 63) == 0) red[tid >> 6] = sum;
  __syncthreads();
  if (tid == 0) {
    float z = red[0] + red[1] + red[2] + red[3];
    float cnt = fmaxf((float)(s1 - s0), 1.0f);
    z /= cnt;
    out[g] = 1.0f / (1.0f + expf(-z));
  }
}

extern "C" void kernel_launch(void* const* d_in, const int* in_sizes, int n_in,
                              void* d_out, int out_size, void* d_ws, size_t ws_size,
                              hipStream_t stream) {
  const float* x   = (const float*)d_in[0];
  const int*   ei  = (const int*)d_in[1];
  const int*   src = ei;               // edge_index[0]
  const int*   dst = ei + N_EDGES;     // edge_index[1]
  const int* batch = (const int*)d_in[2];
  const float* W1  = (const float*)d_in[3];
  const float* W2  = (const float*)d_in[4];
  const float* Wfc = (const float*)d_in[5];
  float* out = (float*)d_out;

  ushort* y16  = (ushort*)d_ws;                          // 6.4M fp16
  ushort* col16 = y16 + (size_t)N_NODES * NF;            // 50000*64 ushort
  int* deg     = (int*)(col16 + (size_t)N_NODES * STRIDE); // 50000
  float* q     = (float*)(deg + N_NODES);                // 50000
  float* v     = q + N_NODES;                            // 128
  uint* ebuf   = (uint*)(v + NF + 32);                   // 800000 u32
  int* bhist   = (int*)(ebuf + N_EDGES);                 // SC_N
  int* R       = bhist + SC_N;                           // SC_N+1
  int* blocksum = R + SC_N + 1;                          // SC_BLOCKS

  const int gemm_grid = (N_NODES + 63) / 64;            // 782
  const int gath_grid = (N_NODES * 64 + 255) / 256;     // 12500
  const int st3_grid  = (SC_N + 255) / 256;             // 300

  // --- build CSR: bin by dst>>7, then per-bin single-block fill ---
  bin_count<<<NBLK, 256, 0, stream>>>(dst, bhist);
  scan_stage1<<<SC_BLOCKS, 256, 0, stream>>>(bhist, R, blocksum);
  scan_stage2<<<1, 256, 0, stream>>>(blocksum);
  scan_stage3<<<st3_grid, 256, 0, stream>>>(R, blocksum);
  bin_scatter<<<NBLK, 256, 0, stream>>>(src, dst, R, ebuf);
  csr_from_bins<<<NBINS, 256, 0, stream>>>(ebuf, R, deg, col16);

  // --- dense GEMM first (linearity: gather and @W1 commute): y16 = x@W1 ---
  w2wfc<<<1, 128, 0, stream>>>(W2, Wfc, v);
  gemm_h16<<<gemm_grid, 256, 0, stream>>>(x, W1, y16, N_NODES);

  // --- conv1 aggregate + relu + (W2@Wfc) dot, all fused per node ---
  gather_qdot<<<gath_grid, 256, 0, stream>>>(y16, deg, col16, v, q);

  // --- conv2 + pool + fc + sigmoid: scalar gather over L2-resident q ---
  pool_q<<<N_GRAPHS, 256, 0, stream>>>(q, deg, col16, batch, out);
}

// Round 12
// 103.756 us; speedup vs baseline: 2.1768x; 1.0831x over previous
//
#include <hip/hip_runtime.h>

#define N_NODES 50000
#define N_EDGES 800000
#define NF 128
#define N_GRAPHS 512
#define STRIDE 64        // fixed CSR slots/node; P(deg>64) ~ 1e-13 for Poisson(16)

#define NBINS 391        // ceil(50000/128) bins of 128 nodes (dst>>7)
#define NBLK 196         // edge blocks: ceil(800000/4096)
#define EPB 4096         // edges per block in binning passes
#define SC_N (NBINS * NBLK)   // 76636 scan elements
#define SC_BLOCKS 38     // ceil(SC_N/2048)

typedef _Float16 f16;
typedef f16 h2   __attribute__((ext_vector_type(2)));
typedef f16 f16x8 __attribute__((ext_vector_type(8)));
typedef float f32x4 __attribute__((ext_vector_type(4)));

union HU { ushort u; _Float16 h; };
__device__ __forceinline__ float h2f(ushort u) { HU x; x.u = u; return (float)x.h; }
__device__ __forceinline__ ushort f2h(float f) { HU x; x.h = (_Float16)f; return x.u; }

// packed fp16 accumulate: 4 v_pk_add_f16 per 16B (vs 16 VALU for cvt+add)
union UH2 { uint u; h2 h; };
__device__ __forceinline__ void acc4h(h2* ah, uint4 u) {
  UH2 c;
  c.u = u.x; ah[0] += c.h;
  c.u = u.y; ah[1] += c.h;
  c.u = u.z; ah[2] += c.h;
  c.u = u.w; ah[3] += c.h;
}

// ---------------- v[f] = sum_j W2[f][j] * Wfc[j] ------------------------------
__global__ __launch_bounds__(128) void w2wfc(const float* __restrict__ W2,
                                             const float* __restrict__ Wfc,
                                             float* __restrict__ v) {
  int f = threadIdx.x;
  float s = 0.f;
  for (int j = 0; j < 128; j += 4) {
    float4 w = ((const float4*)(W2 + f * 128))[j >> 2];
    float4 c = ((const float4*)Wfc)[j >> 2];
    s += w.x * c.x + w.y * c.y + w.z * c.z + w.w * c.w;
  }
  v[f] = s;
}

// ---------------- W1 (f32 [k][n]) -> W1T (fp16 [n][k]) ------------------------
__global__ __launch_bounds__(256) void w1cvt(const float* __restrict__ W1,
                                             ushort* __restrict__ W1T) {
  int i = blockIdx.x * 256 + threadIdx.x;   // 64 blocks x 256 = 16384
  int n = i >> 7, k = i & 127;
  W1T[i] = f2h(W1[k * 128 + n]);
}

// ======== CSR build, phase A: bin edges by dst>>7 (128-node bins) ============
__global__ __launch_bounds__(256) void bin_count(const int* __restrict__ dst,
                                                 int* __restrict__ bhist) {
  __shared__ int hist[NBINS];
  for (int i = threadIdx.x; i < NBINS; i += 256) hist[i] = 0;
  __syncthreads();
  int e0 = blockIdx.x * EPB;
  int e1 = e0 + EPB; if (e1 > N_EDGES) e1 = N_EDGES;
  for (int e = e0 + threadIdx.x; e < e1; e += 256)
    atomicAdd(&hist[dst[e] >> 7], 1);
  __syncthreads();
  for (int i = threadIdx.x; i < NBINS; i += 256)
    bhist[i * NBLK + blockIdx.x] = hist[i];
}

__device__ __forceinline__ int block_incl_scan_256(int v, int* warp_sums) {
  const int tid = threadIdx.x;
  const int lane = tid & 63;
  const int w = tid >> 6;
#pragma unroll
  for (int off = 1; off < 64; off <<= 1) {
    int t = __shfl_up(v, off, 64);
    if (lane >= off) v += t;
  }
  if (lane == 63) warp_sums[w] = v;
  __syncthreads();
  int ws = 0;
#pragma unroll
  for (int i = 0; i < 4; ++i) ws += (i < w) ? warp_sums[i] : 0;
  return v + ws;
}

__global__ __launch_bounds__(256) void scan_stage1(const int* __restrict__ in,
                                                   int* __restrict__ R,
                                                   int* __restrict__ blocksum) {
  __shared__ int warp_sums[4];
  int tid = threadIdx.x;
  int i0 = blockIdx.x * 2048 + tid * 8;
  int v[8];
  int s = 0;
#pragma unroll
  for (int k = 0; k < 8; ++k) {
    int idx = i0 + k;
    v[k] = (idx < SC_N) ? in[idx] : 0;
    s += v[k];
  }
  int incl = block_incl_scan_256(s, warp_sums);
  int run = incl - s;
#pragma unroll
  for (int k = 0; k < 8; ++k) {
    run += v[k];
    int idx = i0 + k;
    if (idx < SC_N) R[idx + 1] = run;
  }
  if (tid == 255) blocksum[blockIdx.x] = incl;   // inclusive block totals
}

// stage3 (merged stage2): add prefix of per-block totals
__global__ __launch_bounds__(256) void scan_stage3(int* __restrict__ R,
                                                   const int* __restrict__ blocksum) {
  int i = blockIdx.x * 256 + threadIdx.x;
  if (i < SC_N) {
    int nb = i >> 11;
    int pre = 0;
    for (int j = 0; j < nb; ++j) pre += blocksum[j];
    R[i + 1] += pre;
  }
  if (i == 0) R[0] = 0;
}

__global__ __launch_bounds__(256) void bin_scatter(const int* __restrict__ src,
                                                   const int* __restrict__ dst,
                                                   const int* __restrict__ R,
                                                   uint* __restrict__ ebuf) {
  __shared__ int cur[NBINS];
  for (int i = threadIdx.x; i < NBINS; i += 256) cur[i] = 0;
  __syncthreads();
  int e0 = blockIdx.x * EPB;
  int e1 = e0 + EPB; if (e1 > N_EDGES) e1 = N_EDGES;
  for (int e = e0 + threadIdx.x; e < e1; e += 256) {
    int d = dst[e];
    int b = d >> 7;
    int loc = atomicAdd(&cur[b], 1);
    ebuf[R[b * NBLK + blockIdx.x] + loc] = ((uint)d << 16) | (uint)src[e];
  }
}

// ======== CSR build, phase B: one block per bin -> col16 window + deg ========
__global__ __launch_bounds__(256) void csr_from_bins(const uint* __restrict__ ebuf,
                                                     const int* __restrict__ R,
                                                     int* __restrict__ deg,
                                                     ushort* __restrict__ col16) {
  __shared__ int dl[128];
  const int bin = blockIdx.x;
  const int n0 = bin << 7;
  if (threadIdx.x < 128) dl[threadIdx.x] = 0;
  __syncthreads();
  int j0 = R[bin * NBLK];
  int j1 = R[(bin + 1) * NBLK];
  for (int j = j0 + threadIdx.x; j < j1; j += 256) {
    uint e = ebuf[j];
    int d = (int)(e >> 16);
    int slot = atomicAdd(&dl[d - n0], 1);
    col16[(size_t)d * STRIDE + slot] = (ushort)(e & 0xFFFFu);
  }
  __syncthreads();
  int cnt = N_NODES - n0; if (cnt > 128) cnt = 128;
  if (threadIdx.x < cnt) deg[n0 + threadIdx.x] = dl[threadIdx.x];
}

// -------- MFMA GEMM: y16 = x @ W1 (fp16 in, f32 acc, fp16 out) ---------------
// 4 waves/block, wave w owns rows [blk*64 + w*16, +16) x all 128 cols.
// A-frag: lane l = row (l&15), k = kc*32 + (l>>4)*8 + e — loaded from x
// (f32, coalesced across the wave) + in-register cvt.  B-frag from W1T
// (fp16 [n][k], 32KB L1-resident): contiguous 16B per lane.
// D layout (verified): col = lane&15, row = (lane>>4)*4 + reg.
__global__ __launch_bounds__(256) void gemm_mfma(const float* __restrict__ x,
                                                 const ushort* __restrict__ W1T,
                                                 ushort* __restrict__ y16, int M) {
  const int tid = threadIdx.x;
  const int w = tid >> 6, l = tid & 63;
  const int row0 = blockIdx.x * 64 + w * 16;
  const int mrow = l & 15, kg = l >> 4;
  const int row = row0 + mrow;

  f32x4 acc[8] = {};
  for (int kc = 0; kc < 4; ++kc) {
    const int cb = kc * 32 + kg * 8;
    f16x8 af = {};
    if (row < M) {
      float4 xlo = *(const float4*)(x + (size_t)row * 128 + cb);
      float4 xhi = *(const float4*)(x + (size_t)row * 128 + cb + 4);
      af[0] = (f16)xlo.x; af[1] = (f16)xlo.y; af[2] = (f16)xlo.z; af[3] = (f16)xlo.w;
      af[4] = (f16)xhi.x; af[5] = (f16)xhi.y; af[6] = (f16)xhi.z; af[7] = (f16)xhi.w;
    }
#pragma unroll
    for (int nt = 0; nt < 8; ++nt) {
      uint4 wb = *(const uint4*)(W1T + ((nt * 16 + mrow) << 7) + cb);
      f16x8 bf = *(const f16x8*)&wb;
      acc[nt] = __builtin_amdgcn_mfma_f32_16x16x32_f16(af, bf, acc[nt], 0, 0, 0);
    }
  }
#pragma unroll
  for (int nt = 0; nt < 8; ++nt) {
#pragma unroll
    for (int r = 0; r < 4; ++r) {
      int rr = row0 + kg * 4 + r;
      if (rr < M) y16[(size_t)rr * 128 + nt * 16 + mrow] = f2h(acc[nt][r]);
    }
  }
}

// ------- gather + relu + dot: q[n] = relu( sum_slots y16[col16[n][j]] ) . v --
// One node per wave64: 4 edge-groups x 16 feat-lanes; packed-fp16 accumulate.
__global__ __launch_bounds__(256) void gather_qdot(const ushort* __restrict__ y16,
                                                   const int* __restrict__ deg,
                                                   const ushort* __restrict__ col16,
                                                   const float* __restrict__ vq,
                                                   float* __restrict__ q) {
  int n = (blockIdx.x * 256 + threadIdx.x) >> 6;
  if (n >= N_NODES) return;
  const int lane = threadIdx.x & 63;
  const int eg = lane >> 4;    // 0..3 edge group
  const int fl = lane & 15;    // feat lane: 8 fp16 = 16B

  int dg = deg[n];
  const ushort* cp = col16 + (size_t)n * STRIDE;
  h2 ah[4] = {};

  int j = eg;
  for (; j + 4 < dg; j += 8) {
    int s0 = cp[j], s1 = cp[j + 4];
    uint4 a = ((const uint4*)y16)[(size_t)s0 * 16 + fl];
    uint4 b = ((const uint4*)y16)[(size_t)s1 * 16 + fl];
    acc4h(ah, a);
    acc4h(ah, b);
  }
  if (j < dg) {
    uint4 a = ((const uint4*)y16)[(size_t)cp[j] * 16 + fl];
    acc4h(ah, a);
  }

  // reduce the 4 edge groups (packed)
#pragma unroll
  for (int k = 0; k < 4; ++k) {
    UH2 c, t;
    c.h = ah[k];
    t.u = (uint)__shfl_xor((int)c.u, 16, 64); ah[k] += t.h;
    c.h = ah[k];
    t.u = (uint)__shfl_xor((int)c.u, 32, 64); ah[k] += t.h;
  }
  // unpack, relu, dot with v (each fl lane owns feats fl*8..fl*8+7)
  float4 v0 = ((const float4*)vq)[fl * 2];
  float4 v1 = ((const float4*)vq)[fl * 2 + 1];
  float p = fmaxf((float)ah[0].x, 0.f) * v0.x + fmaxf((float)ah[0].y, 0.f) * v0.y +
            fmaxf((float)ah[1].x, 0.f) * v0.z + fmaxf((float)ah[1].y, 0.f) * v0.w +
            fmaxf((float)ah[2].x, 0.f) * v1.x + fmaxf((float)ah[2].y, 0.f) * v1.y +
            fmaxf((float)ah[3].x, 0.f) * v1.z + fmaxf((float)ah[3].y, 0.f) * v1.w;
  p += __shfl_xor(p, 1, 64);
  p += __shfl_xor(p, 2, 64);
  p += __shfl_xor(p, 4, 64);
  p += __shfl_xor(p, 8, 64);
  if (lane == 0) q[n] = p;
}

// ------- pool: out[g] = sigmoid( (sum over graph-g edges of q[src]) / cnt ) --
__global__ __launch_bounds__(256) void pool_q(const float* __restrict__ q,
                                              const int* __restrict__ deg,
                                              const ushort* __restrict__ col16,
                                              const int* __restrict__ batch,
                                              float* __restrict__ out) {
  __shared__ float red[4];
  int g = blockIdx.x, tid = threadIdx.x;

  int lo = 0, hi = N_NODES;
  while (lo < hi) { int m = (lo + hi) >> 1; if (batch[m] < g) lo = m + 1; else hi = m; }
  int s0 = lo;
  lo = 0; hi = N_NODES;
  while (lo < hi) { int m = (lo + hi) >> 1; if (batch[m] <= g) lo = m + 1; else hi = m; }
  int s1 = lo;

  float sum = 0.f;
  for (int n = s0 + (tid >> 3); n < s1; n += 32) {
    int dg = deg[n];
    const ushort* cp = col16 + (size_t)n * STRIDE;
    for (int j = tid & 7; j < dg; j += 8) sum += q[cp[j]];
  }
#pragma unroll
  for (int off = 32; off > 0; off >>= 1) sum += __shfl_down(sum, off, 64);
  if ((tid & 63) == 0) red[tid >> 6] = sum;
  __syncthreads();
  if (tid == 0) {
    float z = red[0] + red[1] + red[2] + red[3];
    float cnt = fmaxf((float)(s1 - s0), 1.0f);
    z /= cnt;
    out[g] = 1.0f / (1.0f + expf(-z));
  }
}

extern "C" void kernel_launch(void* const* d_in, const int* in_sizes, int n_in,
                              void* d_out, int out_size, void* d_ws, size_t ws_size,
                              hipStream_t stream) {
  const float* x   = (const float*)d_in[0];
  const int*   ei  = (const int*)d_in[1];
  const int*   src = ei;               // edge_index[0]
  const int*   dst = ei + N_EDGES;     // edge_index[1]
  const int* batch = (const int*)d_in[2];
  const float* W1  = (const float*)d_in[3];
  const float* W2  = (const float*)d_in[4];
  const float* Wfc = (const float*)d_in[5];
  float* out = (float*)d_out;

  ushort* y16  = (ushort*)d_ws;                          // 6.4M fp16
  ushort* col16 = y16 + (size_t)N_NODES * NF;            // 50000*64 ushort
  int* deg     = (int*)(col16 + (size_t)N_NODES * STRIDE); // 50000
  float* q     = (float*)(deg + N_NODES);                // 50000
  float* v     = q + N_NODES;                            // 128
  ushort* W1T  = (ushort*)(v + NF + 32);                 // 16384 fp16
  uint* ebuf   = (uint*)(W1T + 16384 + 64);              // 800000 u32
  int* bhist   = (int*)(ebuf + N_EDGES);                 // SC_N
  int* R       = bhist + SC_N;                           // SC_N+1
  int* blocksum = R + SC_N + 1;                          // SC_BLOCKS

  const int gemm_grid = (N_NODES + 63) / 64;            // 782
  const int gath_grid = (N_NODES * 64 + 255) / 256;     // 12500
  const int st3_grid  = (SC_N + 255) / 256;             // 300

  // --- build CSR: bin by dst>>7, then per-bin single-block fill ---
  bin_count<<<NBLK, 256, 0, stream>>>(dst, bhist);
  scan_stage1<<<SC_BLOCKS, 256, 0, stream>>>(bhist, R, blocksum);
  scan_stage3<<<st3_grid, 256, 0, stream>>>(R, blocksum);
  bin_scatter<<<NBLK, 256, 0, stream>>>(src, dst, R, ebuf);
  csr_from_bins<<<NBINS, 256, 0, stream>>>(ebuf, R, deg, col16);

  // --- weights prep + dense MFMA GEMM: y16 = x@W1 ---
  w2wfc<<<1, 128, 0, stream>>>(W2, Wfc, v);
  w1cvt<<<64, 256, 0, stream>>>(W1, W1T);
  gemm_mfma<<<gemm_grid, 256, 0, stream>>>(x, W1T, y16, N_NODES);

  // --- conv1 aggregate + relu + (W2@Wfc) dot, fused per node ---
  gather_qdot<<<gath_grid, 256, 0, stream>>>(y16, deg, col16, v, q);

  // --- conv2 + pool + fc + sigmoid: scalar gather over L2-resident q ---
  pool_q<<<N_GRAPHS, 256, 0, stream>>>(q, deg, col16, batch, out);
}